// Round 1
// baseline (3093.953 us; speedup 1.0000x reference)
//
#include <hip/hip_runtime.h>
#include <hip/hip_bf16.h>
#include <math.h>

#define SEQ 1024
#define DIM 4096
#define NH 32
#define HD 128
#define NKVH 8
#define FF 14336
#define LR 16

typedef __attribute__((ext_vector_type(8))) short bf16x8;
typedef __attribute__((ext_vector_type(4))) float f32x4;
typedef __attribute__((ext_vector_type(4))) ushort ushort4v;

__device__ __forceinline__ ushort f2bf(float f) {
  union { float f; unsigned u; } v; v.f = f;
  unsigned r = (v.u + 0x7FFFu + ((v.u >> 16) & 1u)) >> 16;
  return (ushort)r;
}
__device__ __forceinline__ float bf2f(ushort h) {
  union { unsigned u; float f; } v; v.u = ((unsigned)h) << 16;
  return v.f;
}

// ---------------- RMSNorm: f32 in -> bf16 out ----------------
__global__ __launch_bounds__(256) void rmsnorm_kernel(const float* __restrict__ x,
                                                      const float* __restrict__ w,
                                                      ushort* __restrict__ out) {
  int row = blockIdx.x;
  int tid = threadIdx.x;
  const float* xr = x + (size_t)row * DIM;
  float vals[16];
  float s = 0.f;
#pragma unroll
  for (int c = 0; c < 4; c++) {
    float4 v = *(const float4*)&xr[(tid + c * 256) * 4];
    vals[c * 4 + 0] = v.x; vals[c * 4 + 1] = v.y;
    vals[c * 4 + 2] = v.z; vals[c * 4 + 3] = v.w;
    s += v.x * v.x + v.y * v.y + v.z * v.z + v.w * v.w;
  }
#pragma unroll
  for (int off = 32; off >= 1; off >>= 1) s += __shfl_down(s, off);
  __shared__ float wsum[4];
  __shared__ float scale_s;
  int lane = tid & 63, wv = tid >> 6;
  if (lane == 0) wsum[wv] = s;
  __syncthreads();
  if (tid == 0) {
    float t = wsum[0] + wsum[1] + wsum[2] + wsum[3];
    scale_s = rsqrtf(t / (float)DIM + 1e-5f);
  }
  __syncthreads();
  float scale = scale_s;
  ushort* orow = out + (size_t)row * DIM;
#pragma unroll
  for (int c = 0; c < 4; c++) {
    int base = (tid + c * 256) * 4;
    float4 wv4 = *(const float4*)&w[base];
    ushort4v ov;
    ov.x = f2bf(vals[c * 4 + 0] * scale * wv4.x);
    ov.y = f2bf(vals[c * 4 + 1] * scale * wv4.y);
    ov.z = f2bf(vals[c * 4 + 2] * scale * wv4.z);
    ov.w = f2bf(vals[c * 4 + 3] * scale * wv4.w);
    *(ushort4v*)&orow[base] = ov;
  }
}

// ---------------- LoRA A: t[M][16] = A(bf16 M x K) @ la(K x 16) ----------------
__global__ __launch_bounds__(256) void lora_a_kernel(const ushort* __restrict__ A,
                                                     const float* __restrict__ la,
                                                     float* __restrict__ t, int K) {
  int m = blockIdx.x;
  int n = threadIdx.x & 15;
  int chunk = threadIdx.x >> 4;  // 0..15
  int kper = K >> 4;
  const ushort* ar = A + (size_t)m * K + (size_t)chunk * kper;
  const float* lap = la + (size_t)chunk * kper * LR + n;
  float s = 0.f;
  for (int k = 0; k < kper; k++) s += bf2f(ar[k]) * lap[(size_t)k * LR];
  __shared__ float red[16][17];
  red[chunk][n] = s;
  __syncthreads();
  if (threadIdx.x < 16) {
    float v = 0.f;
#pragma unroll
    for (int c = 0; c < 16; c++) v += red[c][threadIdx.x];
    t[(size_t)m * LR + threadIdx.x] = v;
  }
}

// ---------------- GEMM + LoRA epilogue ----------------
// out = A(M x K, bf16) @ W(N x K, f32)^T + t(M x 16) @ lb(16 x N)  [+ res]
// MODE 0: bf16 out [M][N];  MODE 1: bf16 out transposed [N][M];  MODE 2: f32 out = v + res
#define BM 128
#define BN 128
#define BK 64

template <int MODE>
__global__ __launch_bounds__(256) void gemm_lora_kernel(
    const ushort* __restrict__ A, const float* __restrict__ W,
    const float* __restrict__ lb, const float* __restrict__ t,
    const float* __restrict__ res, void* __restrict__ outp,
    int M, int N, int K) {
  __shared__ ushort As[BM][72];
  __shared__ ushort Bs[BN][72];
  __shared__ float LB[LR][BN];
  __shared__ float TT[BM][LR];
  int tid = threadIdx.x;
  int lane = tid & 63, wave = tid >> 6;
  int wr = wave >> 1, wc = wave & 1;
  int m0 = blockIdx.y * BM, n0 = blockIdx.x * BN;

  // stage lora tiles once
#pragma unroll
  for (int i = 0; i < 8; i++) {
    int e = tid * 8 + i;
    LB[e >> 7][e & 127] = lb[(size_t)(e >> 7) * N + n0 + (e & 127)];
    TT[e >> 4][e & 15] = t[(size_t)(m0 + (e >> 4)) * LR + (e & 15)];
  }

  int arow = tid >> 1;           // 0..127
  int ak = (tid & 1) * 32;       // 0 or 32
  const ushort* Ab = A + (size_t)(m0 + arow) * K + ak;
  const float* Wb = W + (size_t)(n0 + arow) * K + ak;

  f32x4 acc[4][4] = {};

  for (int kt = 0; kt < K; kt += BK) {
#pragma unroll
    for (int c = 0; c < 4; c++)
      *(bf16x8*)&As[arow][ak + c * 8] = *(const bf16x8*)&Ab[kt + c * 8];
#pragma unroll
    for (int c = 0; c < 8; c++) {
      float4 wv4 = *(const float4*)&Wb[kt + c * 4];
      ushort4v b4;
      b4.x = f2bf(wv4.x); b4.y = f2bf(wv4.y);
      b4.z = f2bf(wv4.z); b4.w = f2bf(wv4.w);
      *(ushort4v*)&Bs[arow][ak + c * 4] = b4;
    }
    __syncthreads();
#pragma unroll
    for (int ks = 0; ks < 2; ks++) {
      bf16x8 af[4], bfr[4];
#pragma unroll
      for (int f = 0; f < 4; f++) {
        af[f] = *(const bf16x8*)&As[wr * 64 + f * 16 + (lane & 15)][ks * 32 + (lane >> 4) * 8];
        bfr[f] = *(const bf16x8*)&Bs[wc * 64 + f * 16 + (lane & 15)][ks * 32 + (lane >> 4) * 8];
      }
#pragma unroll
      for (int fm = 0; fm < 4; fm++)
#pragma unroll
        for (int fn = 0; fn < 4; fn++)
          acc[fm][fn] = __builtin_amdgcn_mfma_f32_16x16x32_bf16(af[fm], bfr[fn], acc[fm][fn], 0, 0, 0);
    }
    __syncthreads();
  }

  // epilogue: + lora, write per MODE
#pragma unroll
  for (int fm = 0; fm < 4; fm++) {
#pragma unroll
    for (int j = 0; j < 4; j++) {
      int ml = wr * 64 + fm * 16 + (lane >> 4) * 4 + j;
      int mg = m0 + ml;
      float tv[LR];
#pragma unroll
      for (int r = 0; r < LR; r++) tv[r] = TT[ml][r];
#pragma unroll
      for (int fn = 0; fn < 4; fn++) {
        int nl = wc * 64 + fn * 16 + (lane & 15);
        int ng = n0 + nl;
        float v = acc[fm][fn][j];
#pragma unroll
        for (int r = 0; r < LR; r++) v += tv[r] * LB[r][nl];
        if (MODE == 0) {
          ((ushort*)outp)[(size_t)mg * N + ng] = f2bf(v);
        } else if (MODE == 1) {
          ((ushort*)outp)[(size_t)ng * M + mg] = f2bf(v);
        } else {
          ((float*)outp)[(size_t)mg * N + ng] = v + res[(size_t)mg * N + ng];
        }
      }
    }
  }
}

// ---------------- RoPE (in-place, bf16), rotate_half, optional scale ----------------
__global__ __launch_bounds__(256) void rope_kernel(ushort* __restrict__ x,
                                                   const float* __restrict__ ct,
                                                   const float* __restrict__ st,
                                                   int nheads, float scale) {
  int idx = blockIdx.x * 256 + threadIdx.x;
  int d = idx & 63;
  int hh = (idx >> 6) % nheads;
  int s = idx / (64 * nheads);
  ushort* p = x + (size_t)s * (nheads * HD) + hh * HD + d;
  float x1 = bf2f(p[0]), x2 = bf2f(p[64]);
  float c = ct[s * HD + d], sn = st[s * HD + d];
  p[0] = f2bf((x1 * c - x2 * sn) * scale);
  p[64] = f2bf((x2 * c + x1 * sn) * scale);
}

// ---------------- Flash attention (causal, GQA 4:1) ----------------
// q: [S][NH*HD] bf16 (pre-scaled by 1/sqrt(HD)); k: [S][NKVH*HD] bf16 (roped)
// vt: [NKVH*HD][S] bf16 (V transposed); o: [S][NH*HD] bf16
__global__ __launch_bounds__(256) void attn_kernel(const ushort* __restrict__ q,
                                                   const ushort* __restrict__ k,
                                                   const ushort* __restrict__ vt,
                                                   ushort* __restrict__ o) {
  int qb = blockIdx.x, h = blockIdx.y, kvh = h >> 2;
  int tid = threadIdx.x, lane = tid & 63, wave = tid >> 6;
  __shared__ ushort Ks[64][136];
  __shared__ ushort Vs[128][72];
  __shared__ ushort Ps[4][16][72];

  bf16x8 qf[4];
  int qrow = qb * 64 + wave * 16 + (lane & 15);
#pragma unroll
  for (int kk = 0; kk < 4; kk++)
    qf[kk] = *(const bf16x8*)&q[(size_t)qrow * DIM + h * HD + kk * 32 + (lane >> 4) * 8];

  f32x4 oacc[8] = {};
  float mrow[4], lrow[4];
  int qr[4];
#pragma unroll
  for (int j = 0; j < 4; j++) {
    mrow[j] = -INFINITY; lrow[j] = 0.f;
    qr[j] = qb * 64 + wave * 16 + (lane >> 4) * 4 + j;
  }

  for (int kt = 0; kt <= qb; kt++) {
    int key0 = kt * 64;
#pragma unroll
    for (int c = 0; c < 4; c++) {
      int e = tid * 32 + c * 8;
      int r = e >> 7, cc = e & 127;
      *(bf16x8*)&Ks[r][cc] =
          *(const bf16x8*)&k[(size_t)(key0 + r) * (NKVH * HD) + kvh * HD + cc];
      int r2 = e >> 6, cc2 = e & 63;
      *(bf16x8*)&Vs[r2][cc2] =
          *(const bf16x8*)&vt[(size_t)(kvh * HD + r2) * SEQ + key0 + cc2];
    }
    __syncthreads();

    f32x4 sf[4] = {};
#pragma unroll
    for (int fn = 0; fn < 4; fn++)
#pragma unroll
      for (int kk = 0; kk < 4; kk++) {
        bf16x8 kf = *(const bf16x8*)&Ks[fn * 16 + (lane & 15)][kk * 32 + (lane >> 4) * 8];
        sf[fn] = __builtin_amdgcn_mfma_f32_16x16x32_bf16(qf[kk], kf, sf[fn], 0, 0, 0);
      }

    // causal mask
#pragma unroll
    for (int fn = 0; fn < 4; fn++) {
      int key = key0 + fn * 16 + (lane & 15);
#pragma unroll
      for (int j = 0; j < 4; j++)
        if (key > qr[j]) sf[fn][j] = -INFINITY;
    }

    // online softmax (rows spread across 16-lane groups)
#pragma unroll
    for (int j = 0; j < 4; j++) {
      float mx = fmaxf(fmaxf(sf[0][j], sf[1][j]), fmaxf(sf[2][j], sf[3][j]));
#pragma unroll
      for (int off = 1; off < 16; off <<= 1) mx = fmaxf(mx, __shfl_xor(mx, off));
      float mnew = fmaxf(mrow[j], mx);
      float sc = __expf(mrow[j] - mnew);
      mrow[j] = mnew;
      float rs = 0.f;
#pragma unroll
      for (int fn = 0; fn < 4; fn++) {
        float p = __expf(sf[fn][j] - mnew);
        sf[fn][j] = p;
        rs += p;
      }
#pragma unroll
      for (int off = 1; off < 16; off <<= 1) rs += __shfl_xor(rs, off);
      lrow[j] = lrow[j] * sc + rs;
#pragma unroll
      for (int f2 = 0; f2 < 8; f2++) oacc[f2][j] *= sc;
    }

    // P to LDS (per-wave private region), then PV
#pragma unroll
    for (int fn = 0; fn < 4; fn++)
#pragma unroll
      for (int j = 0; j < 4; j++)
        Ps[wave][(lane >> 4) * 4 + j][fn * 16 + (lane & 15)] = f2bf(sf[fn][j]);

#pragma unroll
    for (int kk = 0; kk < 2; kk++) {
      bf16x8 pf = *(const bf16x8*)&Ps[wave][lane & 15][kk * 32 + (lane >> 4) * 8];
#pragma unroll
      for (int f2 = 0; f2 < 8; f2++) {
        bf16x8 vf = *(const bf16x8*)&Vs[f2 * 16 + (lane & 15)][kk * 32 + (lane >> 4) * 8];
        oacc[f2] = __builtin_amdgcn_mfma_f32_16x16x32_bf16(pf, vf, oacc[f2], 0, 0, 0);
      }
    }
    __syncthreads();
  }

#pragma unroll
  for (int j = 0; j < 4; j++) {
    float inv = 1.f / lrow[j];
#pragma unroll
    for (int f2 = 0; f2 < 8; f2++)
      o[(size_t)qr[j] * DIM + h * HD + f2 * 16 + (lane & 15)] = f2bf(oacc[f2][j] * inv);
  }
}

// ---------------- h = silu(gate) * up ----------------
__global__ __launch_bounds__(256) void silu_mul_kernel(const ushort* __restrict__ g,
                                                       const ushort* __restrict__ u,
                                                       ushort* __restrict__ h) {
  size_t idx = (size_t)(blockIdx.x * 256 + threadIdx.x) * 8;
  bf16x8 gv = *(const bf16x8*)&g[idx];
  bf16x8 uv = *(const bf16x8*)&u[idx];
  bf16x8 hv;
#pragma unroll
  for (int i = 0; i < 8; i++) {
    float gf = bf2f((ushort)gv[i]);
    float uf = bf2f((ushort)uv[i]);
    float sv = gf / (1.f + __expf(-gf));
    hv[i] = (short)f2bf(sv * uf);
  }
  *(bf16x8*)&h[idx] = hv;
}

extern "C" void kernel_launch(void* const* d_in, const int* in_sizes, int n_in,
                              void* d_out, int out_size, void* d_ws, size_t ws_size,
                              hipStream_t stream) {
  const float* x    = (const float*)d_in[0];
  const float* w1   = (const float*)d_in[1];
  const float* w2   = (const float*)d_in[2];
  const float* cosT = (const float*)d_in[3];
  const float* sinT = (const float*)d_in[4];
  const float* wq = (const float*)d_in[6];
  const float* la_q = (const float*)d_in[7];
  const float* lb_q = (const float*)d_in[8];
  const float* wk = (const float*)d_in[9];
  const float* la_k = (const float*)d_in[10];
  const float* lb_k = (const float*)d_in[11];
  const float* wv = (const float*)d_in[12];
  const float* la_v = (const float*)d_in[13];
  const float* lb_v = (const float*)d_in[14];
  const float* wo = (const float*)d_in[15];
  const float* la_o = (const float*)d_in[16];
  const float* lb_o = (const float*)d_in[17];
  const float* wg = (const float*)d_in[18];
  const float* la_g = (const float*)d_in[19];
  const float* lb_g = (const float*)d_in[20];
  const float* wu = (const float*)d_in[21];
  const float* la_u = (const float*)d_in[22];
  const float* lb_u = (const float*)d_in[23];
  const float* wd = (const float*)d_in[24];
  const float* la_d = (const float*)d_in[25];
  const float* lb_d = (const float*)d_in[26];
  float* out = (float*)d_out;

  char* ws = (char*)d_ws;
  ushort* xn1 = (ushort*)ws;  ws += (size_t)SEQ * DIM * 2;
  ushort* qb  = (ushort*)ws;  ws += (size_t)SEQ * DIM * 2;
  ushort* kb  = (ushort*)ws;  ws += (size_t)SEQ * NKVH * HD * 2;
  ushort* vtb = (ushort*)ws;  ws += (size_t)SEQ * NKVH * HD * 2;
  ushort* ob  = (ushort*)ws;  ws += (size_t)SEQ * DIM * 2;
  float*  xmed= (float*)ws;   ws += (size_t)SEQ * DIM * 4;
  ushort* xn2 = (ushort*)ws;  ws += (size_t)SEQ * DIM * 2;
  ushort* gate= (ushort*)ws;  ws += (size_t)SEQ * FF * 2;
  ushort* up  = (ushort*)ws;  ws += (size_t)SEQ * FF * 2;
  ushort* hb  = (ushort*)ws;  ws += (size_t)SEQ * FF * 2;
  float* t_q = (float*)ws; ws += SEQ * LR * 4;
  float* t_k = (float*)ws; ws += SEQ * LR * 4;
  float* t_v = (float*)ws; ws += SEQ * LR * 4;
  float* t_o = (float*)ws; ws += SEQ * LR * 4;
  float* t_g = (float*)ws; ws += SEQ * LR * 4;
  float* t_u = (float*)ws; ws += SEQ * LR * 4;
  float* t_d = (float*)ws; ws += SEQ * LR * 4;

  // 1) xn1 = rms(x) * w1
  rmsnorm_kernel<<<SEQ, 256, 0, stream>>>(x, w1, xn1);
  // 2) lora-A projections of xn1
  lora_a_kernel<<<SEQ, 256, 0, stream>>>(xn1, la_q, t_q, DIM);
  lora_a_kernel<<<SEQ, 256, 0, stream>>>(xn1, la_k, t_k, DIM);
  lora_a_kernel<<<SEQ, 256, 0, stream>>>(xn1, la_v, t_v, DIM);
  // 3) QKV GEMMs (V written transposed)
  gemm_lora_kernel<0><<<dim3(DIM / BN, SEQ / BM), 256, 0, stream>>>(
      xn1, wq, lb_q, t_q, nullptr, qb, SEQ, DIM, DIM);
  gemm_lora_kernel<0><<<dim3(NKVH * HD / BN, SEQ / BM), 256, 0, stream>>>(
      xn1, wk, lb_k, t_k, nullptr, kb, SEQ, NKVH * HD, DIM);
  gemm_lora_kernel<1><<<dim3(NKVH * HD / BN, SEQ / BM), 256, 0, stream>>>(
      xn1, wv, lb_v, t_v, nullptr, vtb, SEQ, NKVH * HD, DIM);
  // 4) RoPE in-place (q also pre-scaled by 1/sqrt(HD))
  rope_kernel<<<SEQ * NH * 64 / 256, 256, 0, stream>>>(qb, cosT, sinT, NH, 0.08838834764831845f);
  rope_kernel<<<SEQ * NKVH * 64 / 256, 256, 0, stream>>>(kb, cosT, sinT, NKVH, 1.0f);
  // 5) causal GQA flash attention
  attn_kernel<<<dim3(SEQ / 64, NH), 256, 0, stream>>>(qb, kb, vtb, ob);
  // 6) WO + residual -> x_med (f32)
  lora_a_kernel<<<SEQ, 256, 0, stream>>>(ob, la_o, t_o, DIM);
  gemm_lora_kernel<2><<<dim3(DIM / BN, SEQ / BM), 256, 0, stream>>>(
      ob, wo, lb_o, t_o, x, xmed, SEQ, DIM, DIM);
  // 7) second norm + FFN
  rmsnorm_kernel<<<SEQ, 256, 0, stream>>>(xmed, w2, xn2);
  lora_a_kernel<<<SEQ, 256, 0, stream>>>(xn2, la_g, t_g, DIM);
  lora_a_kernel<<<SEQ, 256, 0, stream>>>(xn2, la_u, t_u, DIM);
  gemm_lora_kernel<0><<<dim3(FF / BN, SEQ / BM), 256, 0, stream>>>(
      xn2, wg, lb_g, t_g, nullptr, gate, SEQ, FF, DIM);
  gemm_lora_kernel<0><<<dim3(FF / BN, SEQ / BM), 256, 0, stream>>>(
      xn2, wu, lb_u, t_u, nullptr, up, SEQ, FF, DIM);
  silu_mul_kernel<<<SEQ * FF / 8 / 256, 256, 0, stream>>>(gate, up, hb);
  lora_a_kernel<<<SEQ, 256, 0, stream>>>(hb, la_d, t_d, FF);
  gemm_lora_kernel<2><<<dim3(DIM / BN, SEQ / BM), 256, 0, stream>>>(
      hb, wd, lb_d, t_d, xmed, out, SEQ, DIM, FF);
}

// Round 2
// 2387.219 us; speedup vs baseline: 1.2960x; 1.2960x over previous
//
#include <hip/hip_runtime.h>
#include <hip/hip_bf16.h>
#include <math.h>

#define SEQ 1024
#define DIM 4096
#define NH 32
#define HD 128
#define NKVH 8
#define FF 14336
#define LR 16

typedef __attribute__((ext_vector_type(8))) short bf16x8;
typedef __attribute__((ext_vector_type(4))) float f32x4;
typedef __attribute__((ext_vector_type(4))) ushort ushort4v;

__device__ __forceinline__ ushort f2bf(float f) {
  union { float f; unsigned u; } v; v.f = f;
  unsigned r = (v.u + 0x7FFFu + ((v.u >> 16) & 1u)) >> 16;
  return (ushort)r;
}
__device__ __forceinline__ float bf2f(ushort h) {
  union { unsigned u; float f; } v; v.u = ((unsigned)h) << 16;
  return v.f;
}

__device__ __forceinline__ void gload_lds16(const void* g, void* l) {
  __builtin_amdgcn_global_load_lds(
      (const __attribute__((address_space(1))) void*)g,
      (__attribute__((address_space(3))) void*)l, 16, 0, 0);
}

// ---------------- weight f32 -> bf16 convert (grid-stride) ----------------
__global__ __launch_bounds__(256) void w_convert_kernel(const float* __restrict__ in,
                                                        ushort* __restrict__ out,
                                                        size_t n8) {
  size_t stride = (size_t)gridDim.x * 256;
  for (size_t i = (size_t)blockIdx.x * 256 + threadIdx.x; i < n8; i += stride) {
    size_t b = i * 8;
    float4 a = *(const float4*)&in[b];
    float4 c = *(const float4*)&in[b + 4];
    bf16x8 o;
    o[0] = (short)f2bf(a.x); o[1] = (short)f2bf(a.y);
    o[2] = (short)f2bf(a.z); o[3] = (short)f2bf(a.w);
    o[4] = (short)f2bf(c.x); o[5] = (short)f2bf(c.y);
    o[6] = (short)f2bf(c.z); o[7] = (short)f2bf(c.w);
    *(bf16x8*)&out[b] = o;
  }
}

// ---------------- RMSNorm: f32 in -> bf16 out ----------------
__global__ __launch_bounds__(256) void rmsnorm_kernel(const float* __restrict__ x,
                                                      const float* __restrict__ w,
                                                      ushort* __restrict__ out) {
  int row = blockIdx.x;
  int tid = threadIdx.x;
  const float* xr = x + (size_t)row * DIM;
  float vals[16];
  float s = 0.f;
#pragma unroll
  for (int c = 0; c < 4; c++) {
    float4 v = *(const float4*)&xr[(tid + c * 256) * 4];
    vals[c * 4 + 0] = v.x; vals[c * 4 + 1] = v.y;
    vals[c * 4 + 2] = v.z; vals[c * 4 + 3] = v.w;
    s += v.x * v.x + v.y * v.y + v.z * v.z + v.w * v.w;
  }
#pragma unroll
  for (int off = 32; off >= 1; off >>= 1) s += __shfl_down(s, off);
  __shared__ float wsum[4];
  __shared__ float scale_s;
  int lane = tid & 63, wv = tid >> 6;
  if (lane == 0) wsum[wv] = s;
  __syncthreads();
  if (tid == 0) {
    float t = wsum[0] + wsum[1] + wsum[2] + wsum[3];
    scale_s = rsqrtf(t / (float)DIM + 1e-5f);
  }
  __syncthreads();
  float scale = scale_s;
  ushort* orow = out + (size_t)row * DIM;
#pragma unroll
  for (int c = 0; c < 4; c++) {
    int base = (tid + c * 256) * 4;
    float4 wv4 = *(const float4*)&w[base];
    ushort4v ov;
    ov.x = f2bf(vals[c * 4 + 0] * scale * wv4.x);
    ov.y = f2bf(vals[c * 4 + 1] * scale * wv4.y);
    ov.z = f2bf(vals[c * 4 + 2] * scale * wv4.z);
    ov.w = f2bf(vals[c * 4 + 3] * scale * wv4.w);
    *(ushort4v*)&orow[base] = ov;
  }
}

// ---------------- LoRA A: t[M][16] = A(bf16 M x K) @ la(K x 16) ----------------
__global__ __launch_bounds__(256) void lora_a_kernel(const ushort* __restrict__ A,
                                                     const float* __restrict__ la,
                                                     float* __restrict__ t, int K) {
  int m = blockIdx.x;
  int n = threadIdx.x & 15;
  int chunk = threadIdx.x >> 4;  // 0..15
  int kper = K >> 4;
  const ushort* ar = A + (size_t)m * K + (size_t)chunk * kper;
  const float* lap = la + (size_t)chunk * kper * LR + n;
  float s = 0.f;
  for (int k = 0; k < kper; k++) s += bf2f(ar[k]) * lap[(size_t)k * LR];
  __shared__ float red[16][17];
  red[chunk][n] = s;
  __syncthreads();
  if (threadIdx.x < 16) {
    float v = 0.f;
#pragma unroll
    for (int c = 0; c < 16; c++) v += red[c][threadIdx.x];
    t[(size_t)m * LR + threadIdx.x] = v;
  }
}

#define BM 128
#define BN 128
#define BK 64

// ---------------- bf16 GEMM + LoRA epilogue (m97 structure) ----------------
// out = A(M x K, bf16) @ W(N x K, bf16)^T + t(M x 16) @ lb(16 x N)  [+ res]
// MODE 0: bf16 out [M][N];  MODE 1: bf16 out transposed [N][M];  MODE 2: f32 out = v + res
template <int MODE>
__global__ __launch_bounds__(256) void gemm_bf16_kernel(
    const ushort* __restrict__ A, const ushort* __restrict__ W,
    const float* __restrict__ lb, const float* __restrict__ t,
    const float* __restrict__ res, void* __restrict__ outp,
    int M, int N, int K) {
  __shared__ __align__(16) ushort As[BM * BK];
  __shared__ __align__(16) ushort Bs[BN * BK];
  __shared__ float LB[LR][BN];
  __shared__ float TT[BM][LR];
  int tid = threadIdx.x;
  int lane = tid & 63, wave = tid >> 6;
  int wr = wave >> 1, wc = wave & 1;
  int m0 = blockIdx.y * BM, n0 = blockIdx.x * BN;

  // stage lora tiles once
#pragma unroll
  for (int i = 0; i < 8; i++) {
    int e = tid * 8 + i;
    LB[e >> 7][e & 127] = lb[(size_t)(e >> 7) * N + n0 + (e & 127)];
    TT[e >> 4][e & 15] = t[(size_t)(m0 + (e >> 4)) * LR + (e & 15)];
  }

  // global_load_lds staging: wave w stages rows [i*32 + w*8, +8), lane l -> row w*8+l/8, col (l%8)*8
  const ushort* Ab = A + (size_t)(m0 + wave * 8 + (lane >> 3)) * K + (lane & 7) * 8;
  const ushort* Wb = W + (size_t)(n0 + wave * 8 + (lane >> 3)) * K + (lane & 7) * 8;
  ushort* AsW = As + wave * 512;  // wave-uniform LDS base; HW adds lane*16B
  ushort* BsW = Bs + wave * 512;

  f32x4 acc[4][4] = {};

  for (int kt = 0; kt < K; kt += BK) {
#pragma unroll
    for (int i = 0; i < 4; i++) {
      gload_lds16(Ab + (size_t)(i * 32) * K + kt, AsW + i * 2048);
      gload_lds16(Wb + (size_t)(i * 32) * K + kt, BsW + i * 2048);
    }
    __syncthreads();
#pragma unroll
    for (int ks = 0; ks < 2; ks++) {
      bf16x8 af[4], bfr[4];
#pragma unroll
      for (int f = 0; f < 4; f++) {
        af[f] = *(const bf16x8*)&As[(wr * 64 + f * 16 + (lane & 15)) * BK + ks * 32 + (lane >> 4) * 8];
        bfr[f] = *(const bf16x8*)&Bs[(wc * 64 + f * 16 + (lane & 15)) * BK + ks * 32 + (lane >> 4) * 8];
      }
#pragma unroll
      for (int fm = 0; fm < 4; fm++)
#pragma unroll
        for (int fn = 0; fn < 4; fn++)
          acc[fm][fn] = __builtin_amdgcn_mfma_f32_16x16x32_bf16(af[fm], bfr[fn], acc[fm][fn], 0, 0, 0);
    }
    __syncthreads();
  }

  // epilogue: + lora, write per MODE
#pragma unroll
  for (int fm = 0; fm < 4; fm++) {
#pragma unroll
    for (int j = 0; j < 4; j++) {
      int ml = wr * 64 + fm * 16 + (lane >> 4) * 4 + j;
      int mg = m0 + ml;
      float tv[LR];
#pragma unroll
      for (int r = 0; r < LR; r++) tv[r] = TT[ml][r];
#pragma unroll
      for (int fn = 0; fn < 4; fn++) {
        int nl = wc * 64 + fn * 16 + (lane & 15);
        int ng = n0 + nl;
        float v = acc[fm][fn][j];
#pragma unroll
        for (int r = 0; r < LR; r++) v += tv[r] * LB[r][nl];
        if (MODE == 0) {
          ((ushort*)outp)[(size_t)mg * N + ng] = f2bf(v);
        } else if (MODE == 1) {
          ((ushort*)outp)[(size_t)ng * M + mg] = f2bf(v);
        } else {
          ((float*)outp)[(size_t)mg * N + ng] = v + res[(size_t)mg * N + ng];
        }
      }
    }
  }
}

// ---------------- old f32-weight GEMM (fallback if ws too small) ----------------
template <int MODE>
__global__ __launch_bounds__(256) void gemm_lora_kernel(
    const ushort* __restrict__ A, const float* __restrict__ W,
    const float* __restrict__ lb, const float* __restrict__ t,
    const float* __restrict__ res, void* __restrict__ outp,
    int M, int N, int K) {
  __shared__ ushort As[BM][72];
  __shared__ ushort Bs[BN][72];
  __shared__ float LB[LR][BN];
  __shared__ float TT[BM][LR];
  int tid = threadIdx.x;
  int lane = tid & 63, wave = tid >> 6;
  int wr = wave >> 1, wc = wave & 1;
  int m0 = blockIdx.y * BM, n0 = blockIdx.x * BN;
#pragma unroll
  for (int i = 0; i < 8; i++) {
    int e = tid * 8 + i;
    LB[e >> 7][e & 127] = lb[(size_t)(e >> 7) * N + n0 + (e & 127)];
    TT[e >> 4][e & 15] = t[(size_t)(m0 + (e >> 4)) * LR + (e & 15)];
  }
  int arow = tid >> 1;
  int ak = (tid & 1) * 32;
  const ushort* Ab = A + (size_t)(m0 + arow) * K + ak;
  const float* Wb = W + (size_t)(n0 + arow) * K + ak;
  f32x4 acc[4][4] = {};
  for (int kt = 0; kt < K; kt += BK) {
#pragma unroll
    for (int c = 0; c < 4; c++)
      *(bf16x8*)&As[arow][ak + c * 8] = *(const bf16x8*)&Ab[kt + c * 8];
#pragma unroll
    for (int c = 0; c < 8; c++) {
      float4 wv4 = *(const float4*)&Wb[kt + c * 4];
      ushort4v b4;
      b4.x = f2bf(wv4.x); b4.y = f2bf(wv4.y);
      b4.z = f2bf(wv4.z); b4.w = f2bf(wv4.w);
      *(ushort4v*)&Bs[arow][ak + c * 4] = b4;
    }
    __syncthreads();
#pragma unroll
    for (int ks = 0; ks < 2; ks++) {
      bf16x8 af[4], bfr[4];
#pragma unroll
      for (int f = 0; f < 4; f++) {
        af[f] = *(const bf16x8*)&As[wr * 64 + f * 16 + (lane & 15)][ks * 32 + (lane >> 4) * 8];
        bfr[f] = *(const bf16x8*)&Bs[wc * 64 + f * 16 + (lane & 15)][ks * 32 + (lane >> 4) * 8];
      }
#pragma unroll
      for (int fm = 0; fm < 4; fm++)
#pragma unroll
        for (int fn = 0; fn < 4; fn++)
          acc[fm][fn] = __builtin_amdgcn_mfma_f32_16x16x32_bf16(af[fm], bfr[fn], acc[fm][fn], 0, 0, 0);
    }
    __syncthreads();
  }
#pragma unroll
  for (int fm = 0; fm < 4; fm++) {
#pragma unroll
    for (int j = 0; j < 4; j++) {
      int ml = wr * 64 + fm * 16 + (lane >> 4) * 4 + j;
      int mg = m0 + ml;
      float tv[LR];
#pragma unroll
      for (int r = 0; r < LR; r++) tv[r] = TT[ml][r];
#pragma unroll
      for (int fn = 0; fn < 4; fn++) {
        int nl = wc * 64 + fn * 16 + (lane & 15);
        int ng = n0 + nl;
        float v = acc[fm][fn][j];
#pragma unroll
        for (int r = 0; r < LR; r++) v += tv[r] * LB[r][nl];
        if (MODE == 0) {
          ((ushort*)outp)[(size_t)mg * N + ng] = f2bf(v);
        } else if (MODE == 1) {
          ((ushort*)outp)[(size_t)ng * M + mg] = f2bf(v);
        } else {
          ((float*)outp)[(size_t)mg * N + ng] = v + res[(size_t)mg * N + ng];
        }
      }
    }
  }
}

// ---------------- RoPE (in-place, bf16), rotate_half, optional scale ----------------
__global__ __launch_bounds__(256) void rope_kernel(ushort* __restrict__ x,
                                                   const float* __restrict__ ct,
                                                   const float* __restrict__ st,
                                                   int nheads, float scale) {
  int idx = blockIdx.x * 256 + threadIdx.x;
  int d = idx & 63;
  int hh = (idx >> 6) % nheads;
  int s = idx / (64 * nheads);
  ushort* p = x + (size_t)s * (nheads * HD) + hh * HD + d;
  float x1 = bf2f(p[0]), x2 = bf2f(p[64]);
  float c = ct[s * HD + d], sn = st[s * HD + d];
  p[0] = f2bf((x1 * c - x2 * sn) * scale);
  p[64] = f2bf((x2 * c + x1 * sn) * scale);
}

// ---------------- Flash attention (causal, GQA 4:1) ----------------
__global__ __launch_bounds__(256) void attn_kernel(const ushort* __restrict__ q,
                                                   const ushort* __restrict__ k,
                                                   const ushort* __restrict__ vt,
                                                   ushort* __restrict__ o) {
  int qb = blockIdx.x, h = blockIdx.y, kvh = h >> 2;
  int tid = threadIdx.x, lane = tid & 63, wave = tid >> 6;
  __shared__ ushort Ks[64][136];
  __shared__ ushort Vs[128][72];
  __shared__ ushort Ps[4][16][72];

  bf16x8 qf[4];
  int qrow = qb * 64 + wave * 16 + (lane & 15);
#pragma unroll
  for (int kk = 0; kk < 4; kk++)
    qf[kk] = *(const bf16x8*)&q[(size_t)qrow * DIM + h * HD + kk * 32 + (lane >> 4) * 8];

  f32x4 oacc[8] = {};
  float mrow[4], lrow[4];
  int qr[4];
#pragma unroll
  for (int j = 0; j < 4; j++) {
    mrow[j] = -INFINITY; lrow[j] = 0.f;
    qr[j] = qb * 64 + wave * 16 + (lane >> 4) * 4 + j;
  }

  for (int kt = 0; kt <= qb; kt++) {
    int key0 = kt * 64;
#pragma unroll
    for (int c = 0; c < 4; c++) {
      int e = tid * 32 + c * 8;
      int r = e >> 7, cc = e & 127;
      *(bf16x8*)&Ks[r][cc] =
          *(const bf16x8*)&k[(size_t)(key0 + r) * (NKVH * HD) + kvh * HD + cc];
      int r2 = e >> 6, cc2 = e & 63;
      *(bf16x8*)&Vs[r2][cc2] =
          *(const bf16x8*)&vt[(size_t)(kvh * HD + r2) * SEQ + key0 + cc2];
    }
    __syncthreads();

    f32x4 sf[4] = {};
#pragma unroll
    for (int fn = 0; fn < 4; fn++)
#pragma unroll
      for (int kk = 0; kk < 4; kk++) {
        bf16x8 kf = *(const bf16x8*)&Ks[fn * 16 + (lane & 15)][kk * 32 + (lane >> 4) * 8];
        sf[fn] = __builtin_amdgcn_mfma_f32_16x16x32_bf16(qf[kk], kf, sf[fn], 0, 0, 0);
      }

#pragma unroll
    for (int fn = 0; fn < 4; fn++) {
      int key = key0 + fn * 16 + (lane & 15);
#pragma unroll
      for (int j = 0; j < 4; j++)
        if (key > qr[j]) sf[fn][j] = -INFINITY;
    }

#pragma unroll
    for (int j = 0; j < 4; j++) {
      float mx = fmaxf(fmaxf(sf[0][j], sf[1][j]), fmaxf(sf[2][j], sf[3][j]));
#pragma unroll
      for (int off = 1; off < 16; off <<= 1) mx = fmaxf(mx, __shfl_xor(mx, off));
      float mnew = fmaxf(mrow[j], mx);
      float sc = __expf(mrow[j] - mnew);
      mrow[j] = mnew;
      float rs = 0.f;
#pragma unroll
      for (int fn = 0; fn < 4; fn++) {
        float p = __expf(sf[fn][j] - mnew);
        sf[fn][j] = p;
        rs += p;
      }
#pragma unroll
      for (int off = 1; off < 16; off <<= 1) rs += __shfl_xor(rs, off);
      lrow[j] = lrow[j] * sc + rs;
#pragma unroll
      for (int f2 = 0; f2 < 8; f2++) oacc[f2][j] *= sc;
    }

#pragma unroll
    for (int fn = 0; fn < 4; fn++)
#pragma unroll
      for (int j = 0; j < 4; j++)
        Ps[wave][(lane >> 4) * 4 + j][fn * 16 + (lane & 15)] = f2bf(sf[fn][j]);

#pragma unroll
    for (int kk = 0; kk < 2; kk++) {
      bf16x8 pf = *(const bf16x8*)&Ps[wave][lane & 15][kk * 32 + (lane >> 4) * 8];
#pragma unroll
      for (int f2 = 0; f2 < 8; f2++) {
        bf16x8 vf = *(const bf16x8*)&Vs[f2 * 16 + (lane & 15)][kk * 32 + (lane >> 4) * 8];
        oacc[f2] = __builtin_amdgcn_mfma_f32_16x16x32_bf16(pf, vf, oacc[f2], 0, 0, 0);
      }
    }
    __syncthreads();
  }

#pragma unroll
  for (int j = 0; j < 4; j++) {
    float inv = 1.f / lrow[j];
#pragma unroll
    for (int f2 = 0; f2 < 8; f2++)
      o[(size_t)qr[j] * DIM + h * HD + f2 * 16 + (lane & 15)] = f2bf(oacc[f2][j] * inv);
  }
}

// ---------------- h = silu(gate) * up ----------------
__global__ __launch_bounds__(256) void silu_mul_kernel(const ushort* __restrict__ g,
                                                       const ushort* __restrict__ u,
                                                       ushort* __restrict__ h) {
  size_t idx = (size_t)(blockIdx.x * 256 + threadIdx.x) * 8;
  bf16x8 gv = *(const bf16x8*)&g[idx];
  bf16x8 uv = *(const bf16x8*)&u[idx];
  bf16x8 hv;
#pragma unroll
  for (int i = 0; i < 8; i++) {
    float gf = bf2f((ushort)gv[i]);
    float uf = bf2f((ushort)uv[i]);
    float sv = gf / (1.f + __expf(-gf));
    hv[i] = (short)f2bf(sv * uf);
  }
  *(bf16x8*)&h[idx] = hv;
}

extern "C" void kernel_launch(void* const* d_in, const int* in_sizes, int n_in,
                              void* d_out, int out_size, void* d_ws, size_t ws_size,
                              hipStream_t stream) {
  const float* x    = (const float*)d_in[0];
  const float* w1   = (const float*)d_in[1];
  const float* w2   = (const float*)d_in[2];
  const float* cosT = (const float*)d_in[3];
  const float* sinT = (const float*)d_in[4];
  const float* wq = (const float*)d_in[6];
  const float* la_q = (const float*)d_in[7];
  const float* lb_q = (const float*)d_in[8];
  const float* wk = (const float*)d_in[9];
  const float* la_k = (const float*)d_in[10];
  const float* lb_k = (const float*)d_in[11];
  const float* wv = (const float*)d_in[12];
  const float* la_v = (const float*)d_in[13];
  const float* lb_v = (const float*)d_in[14];
  const float* wo = (const float*)d_in[15];
  const float* la_o = (const float*)d_in[16];
  const float* lb_o = (const float*)d_in[17];
  const float* wg = (const float*)d_in[18];
  const float* la_g = (const float*)d_in[19];
  const float* lb_g = (const float*)d_in[20];
  const float* wu = (const float*)d_in[21];
  const float* la_u = (const float*)d_in[22];
  const float* lb_u = (const float*)d_in[23];
  const float* wd = (const float*)d_in[24];
  const float* la_d = (const float*)d_in[25];
  const float* lb_d = (const float*)d_in[26];
  float* out = (float*)d_out;

  char* ws = (char*)d_ws;
  ushort* xn1 = (ushort*)ws;  ws += (size_t)SEQ * DIM * 2;
  ushort* qb  = (ushort*)ws;  ws += (size_t)SEQ * DIM * 2;
  ushort* kb  = (ushort*)ws;  ws += (size_t)SEQ * NKVH * HD * 2;
  ushort* vtb = (ushort*)ws;  ws += (size_t)SEQ * NKVH * HD * 2;
  ushort* ob  = (ushort*)ws;  ws += (size_t)SEQ * DIM * 2;
  float*  xmed= (float*)ws;   ws += (size_t)SEQ * DIM * 4;
  ushort* xn2 = (ushort*)ws;  ws += (size_t)SEQ * DIM * 2;
  ushort* gate= (ushort*)ws;  ws += (size_t)SEQ * FF * 2;
  ushort* up  = (ushort*)ws;  ws += (size_t)SEQ * FF * 2;
  ushort* hb  = (ushort*)ws;  ws += (size_t)SEQ * FF * 2;
  float* t_q = (float*)ws; ws += SEQ * LR * 4;
  float* t_k = (float*)ws; ws += SEQ * LR * 4;
  float* t_v = (float*)ws; ws += SEQ * LR * 4;
  float* t_o = (float*)ws; ws += SEQ * LR * 4;
  float* t_g = (float*)ws; ws += SEQ * LR * 4;
  float* t_u = (float*)ws; ws += SEQ * LR * 4;
  float* t_d = (float*)ws; ws += SEQ * LR * 4;
  // rotating bf16 weight buffer (max weight = FF x DIM)
  ushort* wbf = (ushort*)ws; ws += (size_t)FF * DIM * 2;
  bool use_bf16 = ((size_t)(ws - (char*)d_ws) <= ws_size);

  auto cvt = [&](const float* w, size_t n) {
    w_convert_kernel<<<2048, 256, 0, stream>>>(w, wbf, n / 8);
  };

  // 1) xn1 = rms(x) * w1
  rmsnorm_kernel<<<SEQ, 256, 0, stream>>>(x, w1, xn1);
  // 2) lora-A projections of xn1
  lora_a_kernel<<<SEQ, 256, 0, stream>>>(xn1, la_q, t_q, DIM);
  lora_a_kernel<<<SEQ, 256, 0, stream>>>(xn1, la_k, t_k, DIM);
  lora_a_kernel<<<SEQ, 256, 0, stream>>>(xn1, la_v, t_v, DIM);

  if (use_bf16) {
    cvt(wq, (size_t)DIM * DIM);
    gemm_bf16_kernel<0><<<dim3(DIM / BN, SEQ / BM), 256, 0, stream>>>(
        xn1, wbf, lb_q, t_q, nullptr, qb, SEQ, DIM, DIM);
    cvt(wk, (size_t)NKVH * HD * DIM);
    gemm_bf16_kernel<0><<<dim3(NKVH * HD / BN, SEQ / BM), 256, 0, stream>>>(
        xn1, wbf, lb_k, t_k, nullptr, kb, SEQ, NKVH * HD, DIM);
    cvt(wv, (size_t)NKVH * HD * DIM);
    gemm_bf16_kernel<1><<<dim3(NKVH * HD / BN, SEQ / BM), 256, 0, stream>>>(
        xn1, wbf, lb_v, t_v, nullptr, vtb, SEQ, NKVH * HD, DIM);
  } else {
    gemm_lora_kernel<0><<<dim3(DIM / BN, SEQ / BM), 256, 0, stream>>>(
        xn1, wq, lb_q, t_q, nullptr, qb, SEQ, DIM, DIM);
    gemm_lora_kernel<0><<<dim3(NKVH * HD / BN, SEQ / BM), 256, 0, stream>>>(
        xn1, wk, lb_k, t_k, nullptr, kb, SEQ, NKVH * HD, DIM);
    gemm_lora_kernel<1><<<dim3(NKVH * HD / BN, SEQ / BM), 256, 0, stream>>>(
        xn1, wv, lb_v, t_v, nullptr, vtb, SEQ, NKVH * HD, DIM);
  }

  // 4) RoPE in-place (q also pre-scaled by 1/sqrt(HD))
  rope_kernel<<<SEQ * NH * 64 / 256, 256, 0, stream>>>(qb, cosT, sinT, NH, 0.08838834764831845f);
  rope_kernel<<<SEQ * NKVH * 64 / 256, 256, 0, stream>>>(kb, cosT, sinT, NKVH, 1.0f);
  // 5) causal GQA flash attention
  attn_kernel<<<dim3(SEQ / 64, NH), 256, 0, stream>>>(qb, kb, vtb, ob);
  // 6) WO + residual -> x_med (f32)
  lora_a_kernel<<<SEQ, 256, 0, stream>>>(ob, la_o, t_o, DIM);
  if (use_bf16) {
    cvt(wo, (size_t)DIM * DIM);
    gemm_bf16_kernel<2><<<dim3(DIM / BN, SEQ / BM), 256, 0, stream>>>(
        ob, wbf, lb_o, t_o, x, xmed, SEQ, DIM, DIM);
  } else {
    gemm_lora_kernel<2><<<dim3(DIM / BN, SEQ / BM), 256, 0, stream>>>(
        ob, wo, lb_o, t_o, x, xmed, SEQ, DIM, DIM);
  }
  // 7) second norm + FFN
  rmsnorm_kernel<<<SEQ, 256, 0, stream>>>(xmed, w2, xn2);
  lora_a_kernel<<<SEQ, 256, 0, stream>>>(xn2, la_g, t_g, DIM);
  lora_a_kernel<<<SEQ, 256, 0, stream>>>(xn2, la_u, t_u, DIM);
  if (use_bf16) {
    cvt(wg, (size_t)FF * DIM);
    gemm_bf16_kernel<0><<<dim3(FF / BN, SEQ / BM), 256, 0, stream>>>(
        xn2, wbf, lb_g, t_g, nullptr, gate, SEQ, FF, DIM);
    cvt(wu, (size_t)FF * DIM);
    gemm_bf16_kernel<0><<<dim3(FF / BN, SEQ / BM), 256, 0, stream>>>(
        xn2, wbf, lb_u, t_u, nullptr, up, SEQ, FF, DIM);
  } else {
    gemm_lora_kernel<0><<<dim3(FF / BN, SEQ / BM), 256, 0, stream>>>(
        xn2, wg, lb_g, t_g, nullptr, gate, SEQ, FF, DIM);
    gemm_lora_kernel<0><<<dim3(FF / BN, SEQ / BM), 256, 0, stream>>>(
        xn2, wu, lb_u, t_u, nullptr, up, SEQ, FF, DIM);
  }
  silu_mul_kernel<<<SEQ * FF / 8 / 256, 256, 0, stream>>>(gate, up, hb);
  lora_a_kernel<<<SEQ, 256, 0, stream>>>(hb, la_d, t_d, FF);
  if (use_bf16) {
    cvt(wd, (size_t)DIM * FF);
    gemm_bf16_kernel<2><<<dim3(DIM / BN, SEQ / BM), 256, 0, stream>>>(
        hb, wbf, lb_d, t_d, xmed, out, SEQ, DIM, FF);
  } else {
    gemm_lora_kernel<2><<<dim3(DIM / BN, SEQ / BM), 256, 0, stream>>>(
        hb, wd, lb_d, t_d, xmed, out, SEQ, DIM, FF);
  }
}

// Round 3
// 1655.400 us; speedup vs baseline: 1.8690x; 1.4421x over previous
//
#include <hip/hip_runtime.h>
#include <hip/hip_bf16.h>
#include <math.h>

#define SEQ 1024
#define DIM 4096
#define NH 32
#define HD 128
#define NKVH 8
#define FF 14336
#define LR 16

typedef __attribute__((ext_vector_type(8))) short bf16x8;
typedef __attribute__((ext_vector_type(4))) float f32x4;
typedef __attribute__((ext_vector_type(4))) ushort ushort4v;

__device__ __forceinline__ ushort f2bf(float f) {
  union { float f; unsigned u; } v; v.f = f;
  unsigned r = (v.u + 0x7FFFu + ((v.u >> 16) & 1u)) >> 16;
  return (ushort)r;
}
__device__ __forceinline__ float bf2f(ushort h) {
  union { unsigned u; float f; } v; v.u = ((unsigned)h) << 16;
  return v.f;
}

__device__ __forceinline__ void gload_lds16(const void* g, void* l) {
  __builtin_amdgcn_global_load_lds(
      (const __attribute__((address_space(1))) void*)g,
      (__attribute__((address_space(3))) void*)l, 16, 0, 0);
}

// ---------------- weight f32 -> bf16 convert (grid-stride) ----------------
__global__ __launch_bounds__(256) void w_convert_kernel(const float* __restrict__ in,
                                                        ushort* __restrict__ out,
                                                        size_t n8) {
  size_t stride = (size_t)gridDim.x * 256;
  for (size_t i = (size_t)blockIdx.x * 256 + threadIdx.x; i < n8; i += stride) {
    size_t b = i * 8;
    float4 a = *(const float4*)&in[b];
    float4 c = *(const float4*)&in[b + 4];
    bf16x8 o;
    o[0] = (short)f2bf(a.x); o[1] = (short)f2bf(a.y);
    o[2] = (short)f2bf(a.z); o[3] = (short)f2bf(a.w);
    o[4] = (short)f2bf(c.x); o[5] = (short)f2bf(c.y);
    o[6] = (short)f2bf(c.z); o[7] = (short)f2bf(c.w);
    *(bf16x8*)&out[b] = o;
  }
}

// ---------------- RMSNorm: f32 in -> bf16 out ----------------
__global__ __launch_bounds__(256) void rmsnorm_kernel(const float* __restrict__ x,
                                                      const float* __restrict__ w,
                                                      ushort* __restrict__ out) {
  int row = blockIdx.x;
  int tid = threadIdx.x;
  const float* xr = x + (size_t)row * DIM;
  float vals[16];
  float s = 0.f;
#pragma unroll
  for (int c = 0; c < 4; c++) {
    float4 v = *(const float4*)&xr[(tid + c * 256) * 4];
    vals[c * 4 + 0] = v.x; vals[c * 4 + 1] = v.y;
    vals[c * 4 + 2] = v.z; vals[c * 4 + 3] = v.w;
    s += v.x * v.x + v.y * v.y + v.z * v.z + v.w * v.w;
  }
#pragma unroll
  for (int off = 32; off >= 1; off >>= 1) s += __shfl_down(s, off);
  __shared__ float wsum[4];
  __shared__ float scale_s;
  int lane = tid & 63, wv = tid >> 6;
  if (lane == 0) wsum[wv] = s;
  __syncthreads();
  if (tid == 0) {
    float t = wsum[0] + wsum[1] + wsum[2] + wsum[3];
    scale_s = rsqrtf(t / (float)DIM + 1e-5f);
  }
  __syncthreads();
  float scale = scale_s;
  ushort* orow = out + (size_t)row * DIM;
#pragma unroll
  for (int c = 0; c < 4; c++) {
    int base = (tid + c * 256) * 4;
    float4 wv4 = *(const float4*)&w[base];
    ushort4v ov;
    ov.x = f2bf(vals[c * 4 + 0] * scale * wv4.x);
    ov.y = f2bf(vals[c * 4 + 1] * scale * wv4.y);
    ov.z = f2bf(vals[c * 4 + 2] * scale * wv4.z);
    ov.w = f2bf(vals[c * 4 + 3] * scale * wv4.w);
    *(ushort4v*)&orow[base] = ov;
  }
}

// ---------------- LoRA A: tbf[M][16] = A(bf16 M x K) @ la(K x 16), bf16 out ----------------
// coalesced: thread i covers contiguous k in [i*16, i*16+16)
__global__ __launch_bounds__(256) void lora_a_kernel(const ushort* __restrict__ A,
                                                     const float* __restrict__ la,
                                                     ushort* __restrict__ tbf, int K) {
  int m = blockIdx.x, i = threadIdx.x;
  float acc[16];
#pragma unroll
  for (int n = 0; n < 16; n++) acc[n] = 0.f;
  for (int base = i * 16; base < K; base += 256 * 16) {
    bf16x8 a0 = *(const bf16x8*)&A[(size_t)m * K + base];
    bf16x8 a1 = *(const bf16x8*)&A[(size_t)m * K + base + 8];
    const float* lp = la + (size_t)base * LR;
#pragma unroll
    for (int kk = 0; kk < 16; kk++) {
      float av = bf2f((ushort)(kk < 8 ? a0[kk] : a1[kk - 8]));
#pragma unroll
      for (int n = 0; n < 16; n += 4) {
        float4 l = *(const float4*)&lp[kk * LR + n];
        acc[n] += av * l.x; acc[n + 1] += av * l.y;
        acc[n + 2] += av * l.z; acc[n + 3] += av * l.w;
      }
    }
  }
  __shared__ float red[256][16];
  __shared__ float red2[16][16];
#pragma unroll
  for (int n = 0; n < 16; n++) red[i][n] = acc[n];
  __syncthreads();
  {
    int g = i >> 4, n = i & 15;
    float s = 0.f;
#pragma unroll
    for (int j = 0; j < 16; j++) s += red[g * 16 + j][n];
    red2[g][n] = s;
  }
  __syncthreads();
  if (i < 16) {
    float s = 0.f;
#pragma unroll
    for (int g = 0; g < 16; g++) s += red2[g][i];
    tbf[(size_t)m * LR + i] = f2bf(s);
  }
}

#define BM 128
#define BN 128
#define BK 64

// ---------------- bf16 GEMM, 2-phase dbuf + counted vmcnt + XOR swizzle ----------------
// out = A(M x K) @ W(N x K)^T + tbf(M x 16) @ lb(16 x N)  [+ res], lora via K-extension
// MODE 0: bf16 [M][N];  MODE 1: bf16 transposed [N][M];  MODE 2: f32 = v + res
template <int MODE>
__global__ __launch_bounds__(256) void gemm_bf16_db(
    const ushort* __restrict__ A, const ushort* __restrict__ W,
    const float* __restrict__ lb, const ushort* __restrict__ tbf,
    const float* __restrict__ res, void* __restrict__ outp,
    int M, int N, int K) {
  __shared__ __align__(16) ushort As[2][BM * BK];
  __shared__ __align__(16) ushort Bs[2][BN * BK];
  int tid = threadIdx.x;
  int lane = tid & 63, wave = tid >> 6;
  int wr = wave >> 1, wc = wave & 1;
  int m0 = blockIdx.y * BM, n0 = blockIdx.x * BN;

  // source pre-swizzle: lane l supplies global col-slot (l&7)^(l>>3) so that
  // LDS[r][phys_slot] holds global slot phys_slot^(r&7)  (linear lane*16B dest)
  int lr = lane >> 3;                       // row within 8-row wave chunk
  int swz = ((lane & 7) ^ lr) * 8;          // element offset of source slot
  const ushort* Ab = A + (size_t)(m0 + wave * 8 + lr) * K + swz;
  const ushort* Wb = W + (size_t)(n0 + wave * 8 + lr) * K + swz;

  f32x4 acc[4][4] = {};
  int nk = K / BK;

#define STAGE(kt, b)                                                      \
  {                                                                       \
    ushort* pa = &As[b][wave * 8 * BK];                                   \
    ushort* pb = &Bs[b][wave * 8 * BK];                                   \
    const ushort* ga = Ab + (kt) * BK;                                    \
    const ushort* gb = Wb + (kt) * BK;                                    \
    _Pragma("unroll") for (int i = 0; i < 4; i++) {                       \
      gload_lds16(ga + (size_t)(i * 32) * K, pa + i * 32 * BK);           \
      gload_lds16(gb + (size_t)(i * 32) * K, pb + i * 32 * BK);           \
    }                                                                     \
  }

  STAGE(0, 0);
  for (int kt = 0; kt < nk; kt++) {
    int cur = kt & 1;
    if (kt + 1 < nk) {
      STAGE(kt + 1, cur ^ 1);
      asm volatile("s_waitcnt vmcnt(8)" ::: "memory");  // my buf[cur] 8 loads done
    } else {
      asm volatile("s_waitcnt vmcnt(0)" ::: "memory");
    }
    __builtin_amdgcn_s_barrier();
    __builtin_amdgcn_sched_barrier(0);
    const ushort* as = As[cur];
    const ushort* bs = Bs[cur];
#pragma unroll
    for (int ks = 0; ks < 2; ks++) {
      bf16x8 af[4], bfr[4];
#pragma unroll
      for (int f = 0; f < 4; f++) {
        int ra = wr * 64 + f * 16 + (lane & 15);
        int rb = wc * 64 + f * 16 + (lane & 15);
        int sl = (ks * 4 + (lane >> 4)) ^ (lane & 7);   // swizzled read slot
        af[f] = *(const bf16x8*)&as[ra * BK + sl * 8];
        bfr[f] = *(const bf16x8*)&bs[rb * BK + sl * 8];
      }
#pragma unroll
      for (int fm = 0; fm < 4; fm++)
#pragma unroll
        for (int fn = 0; fn < 4; fn++)
          acc[fm][fn] = __builtin_amdgcn_mfma_f32_16x16x32_bf16(af[fm], bfr[fn], acc[fm][fn], 0, 0, 0);
    }
    asm volatile("" ::: "memory");
    __builtin_amdgcn_s_barrier();
    __builtin_amdgcn_sched_barrier(0);
  }
#undef STAGE

  // ---- LoRA K-extension: one K=32 slice, A-frag = [t | 0], B-frag = [lb^T | 0] ----
  // write swizzled into As[0]/Bs[0] (all waves are past the final barrier)
  for (int task = tid; task < 512; task += 256) {
    int r = task >> 2, ls = task & 3;          // row, logical slot (8 elems)
    int ph = ls ^ (r & 7);                     // physical slot
    bf16x8 avv = {};
    bf16x8 bvv = {};
    if (ls < 2) {
      avv = *(const bf16x8*)&tbf[(size_t)(m0 + r) * LR + ls * 8];
#pragma unroll
      for (int j = 0; j < 8; j++)
        bvv[j] = (short)f2bf(lb[(size_t)(ls * 8 + j) * N + n0 + r]);
    }
    *(bf16x8*)&As[0][r * BK + ph * 8] = avv;
    *(bf16x8*)&Bs[0][r * BK + ph * 8] = bvv;
  }
  __syncthreads();
  {
    bf16x8 af[4], bfr[4];
#pragma unroll
    for (int f = 0; f < 4; f++) {
      int ra = wr * 64 + f * 16 + (lane & 15);
      int rb = wc * 64 + f * 16 + (lane & 15);
      int sl = (lane >> 4) ^ (lane & 7);
      af[f] = *(const bf16x8*)&As[0][ra * BK + sl * 8];
      bfr[f] = *(const bf16x8*)&Bs[0][rb * BK + sl * 8];
    }
#pragma unroll
    for (int fm = 0; fm < 4; fm++)
#pragma unroll
      for (int fn = 0; fn < 4; fn++)
        acc[fm][fn] = __builtin_amdgcn_mfma_f32_16x16x32_bf16(af[fm], bfr[fn], acc[fm][fn], 0, 0, 0);
  }

  // ---- epilogue: pure store ----
#pragma unroll
  for (int fm = 0; fm < 4; fm++) {
#pragma unroll
    for (int j = 0; j < 4; j++) {
      int mg = m0 + wr * 64 + fm * 16 + (lane >> 4) * 4 + j;
#pragma unroll
      for (int fn = 0; fn < 4; fn++) {
        int ng = n0 + wc * 64 + fn * 16 + (lane & 15);
        float v = acc[fm][fn][j];
        if (MODE == 0) {
          ((ushort*)outp)[(size_t)mg * N + ng] = f2bf(v);
        } else if (MODE == 1) {
          ((ushort*)outp)[(size_t)ng * M + mg] = f2bf(v);
        } else {
          ((float*)outp)[(size_t)mg * N + ng] = v + res[(size_t)mg * N + ng];
        }
      }
    }
  }
}

// ---------------- RoPE (in-place, bf16), rotate_half, optional scale ----------------
__global__ __launch_bounds__(256) void rope_kernel(ushort* __restrict__ x,
                                                   const float* __restrict__ ct,
                                                   const float* __restrict__ st,
                                                   int nheads, float scale) {
  int idx = blockIdx.x * 256 + threadIdx.x;
  int d = idx & 63;
  int hh = (idx >> 6) % nheads;
  int s = idx / (64 * nheads);
  ushort* p = x + (size_t)s * (nheads * HD) + hh * HD + d;
  float x1 = bf2f(p[0]), x2 = bf2f(p[64]);
  float c = ct[s * HD + d], sn = st[s * HD + d];
  p[0] = f2bf((x1 * c - x2 * sn) * scale);
  p[64] = f2bf((x2 * c + x1 * sn) * scale);
}

// ---------------- Flash attention (causal, GQA 4:1) ----------------
__global__ __launch_bounds__(256) void attn_kernel(const ushort* __restrict__ q,
                                                   const ushort* __restrict__ k,
                                                   const ushort* __restrict__ vt,
                                                   ushort* __restrict__ o) {
  int qb = blockIdx.x, h = blockIdx.y, kvh = h >> 2;
  int tid = threadIdx.x, lane = tid & 63, wave = tid >> 6;
  __shared__ ushort Ks[64][136];
  __shared__ ushort Vs[128][72];
  __shared__ ushort Ps[4][16][72];

  bf16x8 qf[4];
  int qrow = qb * 64 + wave * 16 + (lane & 15);
#pragma unroll
  for (int kk = 0; kk < 4; kk++)
    qf[kk] = *(const bf16x8*)&q[(size_t)qrow * DIM + h * HD + kk * 32 + (lane >> 4) * 8];

  f32x4 oacc[8] = {};
  float mrow[4], lrow[4];
  int qr[4];
#pragma unroll
  for (int j = 0; j < 4; j++) {
    mrow[j] = -INFINITY; lrow[j] = 0.f;
    qr[j] = qb * 64 + wave * 16 + (lane >> 4) * 4 + j;
  }

  for (int kt = 0; kt <= qb; kt++) {
    int key0 = kt * 64;
#pragma unroll
    for (int c = 0; c < 4; c++) {
      int e = tid * 32 + c * 8;
      int r = e >> 7, cc = e & 127;
      *(bf16x8*)&Ks[r][cc] =
          *(const bf16x8*)&k[(size_t)(key0 + r) * (NKVH * HD) + kvh * HD + cc];
      int r2 = e >> 6, cc2 = e & 63;
      *(bf16x8*)&Vs[r2][cc2] =
          *(const bf16x8*)&vt[(size_t)(kvh * HD + r2) * SEQ + key0 + cc2];
    }
    __syncthreads();

    f32x4 sf[4] = {};
#pragma unroll
    for (int fn = 0; fn < 4; fn++)
#pragma unroll
      for (int kk = 0; kk < 4; kk++) {
        bf16x8 kf = *(const bf16x8*)&Ks[fn * 16 + (lane & 15)][kk * 32 + (lane >> 4) * 8];
        sf[fn] = __builtin_amdgcn_mfma_f32_16x16x32_bf16(qf[kk], kf, sf[fn], 0, 0, 0);
      }

#pragma unroll
    for (int fn = 0; fn < 4; fn++) {
      int key = key0 + fn * 16 + (lane & 15);
#pragma unroll
      for (int j = 0; j < 4; j++)
        if (key > qr[j]) sf[fn][j] = -INFINITY;
    }

#pragma unroll
    for (int j = 0; j < 4; j++) {
      float mx = fmaxf(fmaxf(sf[0][j], sf[1][j]), fmaxf(sf[2][j], sf[3][j]));
#pragma unroll
      for (int off = 1; off < 16; off <<= 1) mx = fmaxf(mx, __shfl_xor(mx, off));
      float mnew = fmaxf(mrow[j], mx);
      float sc = __expf(mrow[j] - mnew);
      mrow[j] = mnew;
      float rs = 0.f;
#pragma unroll
      for (int fn = 0; fn < 4; fn++) {
        float p = __expf(sf[fn][j] - mnew);
        sf[fn][j] = p;
        rs += p;
      }
#pragma unroll
      for (int off = 1; off < 16; off <<= 1) rs += __shfl_xor(rs, off);
      lrow[j] = lrow[j] * sc + rs;
#pragma unroll
      for (int f2 = 0; f2 < 8; f2++) oacc[f2][j] *= sc;
    }

#pragma unroll
    for (int fn = 0; fn < 4; fn++)
#pragma unroll
      for (int j = 0; j < 4; j++)
        Ps[wave][(lane >> 4) * 4 + j][fn * 16 + (lane & 15)] = f2bf(sf[fn][j]);

#pragma unroll
    for (int kk = 0; kk < 2; kk++) {
      bf16x8 pf = *(const bf16x8*)&Ps[wave][lane & 15][kk * 32 + (lane >> 4) * 8];
#pragma unroll
      for (int f2 = 0; f2 < 8; f2++) {
        bf16x8 vf = *(const bf16x8*)&Vs[f2 * 16 + (lane & 15)][kk * 32 + (lane >> 4) * 8];
        oacc[f2] = __builtin_amdgcn_mfma_f32_16x16x32_bf16(pf, vf, oacc[f2], 0, 0, 0);
      }
    }
    __syncthreads();
  }

#pragma unroll
  for (int j = 0; j < 4; j++) {
    float inv = 1.f / lrow[j];
#pragma unroll
    for (int f2 = 0; f2 < 8; f2++)
      o[(size_t)qr[j] * DIM + h * HD + f2 * 16 + (lane & 15)] = f2bf(oacc[f2][j] * inv);
  }
}

// ---------------- h = silu(gate) * up ----------------
__global__ __launch_bounds__(256) void silu_mul_kernel(const ushort* __restrict__ g,
                                                       const ushort* __restrict__ u,
                                                       ushort* __restrict__ h) {
  size_t idx = (size_t)(blockIdx.x * 256 + threadIdx.x) * 8;
  bf16x8 gv = *(const bf16x8*)&g[idx];
  bf16x8 uv = *(const bf16x8*)&u[idx];
  bf16x8 hv;
#pragma unroll
  for (int i = 0; i < 8; i++) {
    float gf = bf2f((ushort)gv[i]);
    float uf = bf2f((ushort)uv[i]);
    float sv = gf / (1.f + __expf(-gf));
    hv[i] = (short)f2bf(sv * uf);
  }
  *(bf16x8*)&h[idx] = hv;
}

extern "C" void kernel_launch(void* const* d_in, const int* in_sizes, int n_in,
                              void* d_out, int out_size, void* d_ws, size_t ws_size,
                              hipStream_t stream) {
  const float* x    = (const float*)d_in[0];
  const float* w1   = (const float*)d_in[1];
  const float* w2   = (const float*)d_in[2];
  const float* cosT = (const float*)d_in[3];
  const float* sinT = (const float*)d_in[4];
  const float* wq = (const float*)d_in[6];
  const float* la_q = (const float*)d_in[7];
  const float* lb_q = (const float*)d_in[8];
  const float* wk = (const float*)d_in[9];
  const float* la_k = (const float*)d_in[10];
  const float* lb_k = (const float*)d_in[11];
  const float* wv = (const float*)d_in[12];
  const float* la_v = (const float*)d_in[13];
  const float* lb_v = (const float*)d_in[14];
  const float* wo = (const float*)d_in[15];
  const float* la_o = (const float*)d_in[16];
  const float* lb_o = (const float*)d_in[17];
  const float* wg = (const float*)d_in[18];
  const float* la_g = (const float*)d_in[19];
  const float* lb_g = (const float*)d_in[20];
  const float* wu = (const float*)d_in[21];
  const float* la_u = (const float*)d_in[22];
  const float* lb_u = (const float*)d_in[23];
  const float* wd = (const float*)d_in[24];
  const float* la_d = (const float*)d_in[25];
  const float* lb_d = (const float*)d_in[26];
  float* out = (float*)d_out;

  char* ws = (char*)d_ws;
  ushort* xn1 = (ushort*)ws;  ws += (size_t)SEQ * DIM * 2;
  ushort* qb  = (ushort*)ws;  ws += (size_t)SEQ * DIM * 2;
  ushort* kb  = (ushort*)ws;  ws += (size_t)SEQ * NKVH * HD * 2;
  ushort* vtb = (ushort*)ws;  ws += (size_t)SEQ * NKVH * HD * 2;
  ushort* ob  = (ushort*)ws;  ws += (size_t)SEQ * DIM * 2;
  float*  xmed= (float*)ws;   ws += (size_t)SEQ * DIM * 4;
  ushort* xn2 = (ushort*)ws;  ws += (size_t)SEQ * DIM * 2;
  ushort* gate= (ushort*)ws;  ws += (size_t)SEQ * FF * 2;
  ushort* up  = (ushort*)ws;  ws += (size_t)SEQ * FF * 2;
  ushort* hb  = (ushort*)ws;  ws += (size_t)SEQ * FF * 2;
  ushort* t_q = (ushort*)ws; ws += SEQ * LR * 2;
  ushort* t_k = (ushort*)ws; ws += SEQ * LR * 2;
  ushort* t_v = (ushort*)ws; ws += SEQ * LR * 2;
  ushort* t_o = (ushort*)ws; ws += SEQ * LR * 2;
  ushort* t_g = (ushort*)ws; ws += SEQ * LR * 2;
  ushort* t_u = (ushort*)ws; ws += SEQ * LR * 2;
  ushort* t_d = (ushort*)ws; ws += SEQ * LR * 2;
  // rotating bf16 weight buffer (max weight = FF x DIM)
  ushort* wbf = (ushort*)ws; ws += (size_t)FF * DIM * 2;

  auto cvt = [&](const float* w, size_t n) {
    w_convert_kernel<<<2048, 256, 0, stream>>>(w, wbf, n / 8);
  };

  // 1) xn1 = rms(x) * w1
  rmsnorm_kernel<<<SEQ, 256, 0, stream>>>(x, w1, xn1);
  // 2) lora-A projections of xn1
  lora_a_kernel<<<SEQ, 256, 0, stream>>>(xn1, la_q, t_q, DIM);
  lora_a_kernel<<<SEQ, 256, 0, stream>>>(xn1, la_k, t_k, DIM);
  lora_a_kernel<<<SEQ, 256, 0, stream>>>(xn1, la_v, t_v, DIM);
  // 3) QKV GEMMs (V written transposed)
  cvt(wq, (size_t)DIM * DIM);
  gemm_bf16_db<0><<<dim3(DIM / BN, SEQ / BM), 256, 0, stream>>>(
      xn1, wbf, lb_q, t_q, nullptr, qb, SEQ, DIM, DIM);
  cvt(wk, (size_t)NKVH * HD * DIM);
  gemm_bf16_db<0><<<dim3(NKVH * HD / BN, SEQ / BM), 256, 0, stream>>>(
      xn1, wbf, lb_k, t_k, nullptr, kb, SEQ, NKVH * HD, DIM);
  cvt(wv, (size_t)NKVH * HD * DIM);
  gemm_bf16_db<1><<<dim3(NKVH * HD / BN, SEQ / BM), 256, 0, stream>>>(
      xn1, wbf, lb_v, t_v, nullptr, vtb, SEQ, NKVH * HD, DIM);
  // 4) RoPE in-place (q also pre-scaled by 1/sqrt(HD))
  rope_kernel<<<SEQ * NH * 64 / 256, 256, 0, stream>>>(qb, cosT, sinT, NH, 0.08838834764831845f);
  rope_kernel<<<SEQ * NKVH * 64 / 256, 256, 0, stream>>>(kb, cosT, sinT, NKVH, 1.0f);
  // 5) causal GQA flash attention
  attn_kernel<<<dim3(SEQ / 64, NH), 256, 0, stream>>>(qb, kb, vtb, ob);
  // 6) WO + residual -> x_med (f32)
  lora_a_kernel<<<SEQ, 256, 0, stream>>>(ob, la_o, t_o, DIM);
  cvt(wo, (size_t)DIM * DIM);
  gemm_bf16_db<2><<<dim3(DIM / BN, SEQ / BM), 256, 0, stream>>>(
      ob, wbf, lb_o, t_o, x, xmed, SEQ, DIM, DIM);
  // 7) second norm + FFN
  rmsnorm_kernel<<<SEQ, 256, 0, stream>>>(xmed, w2, xn2);
  lora_a_kernel<<<SEQ, 256, 0, stream>>>(xn2, la_g, t_g, DIM);
  lora_a_kernel<<<SEQ, 256, 0, stream>>>(xn2, la_u, t_u, DIM);
  cvt(wg, (size_t)FF * DIM);
  gemm_bf16_db<0><<<dim3(FF / BN, SEQ / BM), 256, 0, stream>>>(
      xn2, wbf, lb_g, t_g, nullptr, gate, SEQ, FF, DIM);
  cvt(wu, (size_t)FF * DIM);
  gemm_bf16_db<0><<<dim3(FF / BN, SEQ / BM), 256, 0, stream>>>(
      xn2, wbf, lb_u, t_u, nullptr, up, SEQ, FF, DIM);
  silu_mul_kernel<<<SEQ * FF / 8 / 256, 256, 0, stream>>>(gate, up, hb);
  lora_a_kernel<<<SEQ, 256, 0, stream>>>(hb, la_d, t_d, FF);
  cvt(wd, (size_t)DIM * FF);
  gemm_bf16_db<2><<<dim3(DIM / BN, SEQ / BM), 256, 0, stream>>>(
      hb, wbf, lb_d, t_d, xmed, out, SEQ, DIM, FF);
}

// Round 4
// 1467.715 us; speedup vs baseline: 2.1080x; 1.1279x over previous
//
#include <hip/hip_runtime.h>
#include <hip/hip_bf16.h>
#include <math.h>

#define SEQ 1024
#define DIM 4096
#define NH 32
#define HD 128
#define NKVH 8
#define FF 14336
#define LR 16

typedef __attribute__((ext_vector_type(8))) short bf16x8;
typedef __attribute__((ext_vector_type(4))) float f32x4;
typedef __attribute__((ext_vector_type(4))) ushort ushort4v;

__device__ __forceinline__ ushort f2bf(float f) {
  union { float f; unsigned u; } v; v.f = f;
  unsigned r = (v.u + 0x7FFFu + ((v.u >> 16) & 1u)) >> 16;
  return (ushort)r;
}
__device__ __forceinline__ float bf2f(ushort h) {
  union { unsigned u; float f; } v; v.u = ((unsigned)h) << 16;
  return v.f;
}

__device__ __forceinline__ void gload_lds16(const void* g, void* l) {
  __builtin_amdgcn_global_load_lds(
      (const __attribute__((address_space(1))) void*)g,
      (__attribute__((address_space(3))) void*)l, 16, 0, 0);
}

// ---------------- weight f32 -> bf16 convert (grid-stride) ----------------
__global__ __launch_bounds__(256) void w_convert_kernel(const float* __restrict__ in,
                                                        ushort* __restrict__ out,
                                                        size_t n8) {
  size_t stride = (size_t)gridDim.x * 256;
  for (size_t i = (size_t)blockIdx.x * 256 + threadIdx.x; i < n8; i += stride) {
    size_t b = i * 8;
    float4 a = *(const float4*)&in[b];
    float4 c = *(const float4*)&in[b + 4];
    bf16x8 o;
    o[0] = (short)f2bf(a.x); o[1] = (short)f2bf(a.y);
    o[2] = (short)f2bf(a.z); o[3] = (short)f2bf(a.w);
    o[4] = (short)f2bf(c.x); o[5] = (short)f2bf(c.y);
    o[6] = (short)f2bf(c.z); o[7] = (short)f2bf(c.w);
    *(bf16x8*)&out[b] = o;
  }
}

// ---------------- RMSNorm: f32 in -> bf16 out ----------------
__global__ __launch_bounds__(256) void rmsnorm_kernel(const float* __restrict__ x,
                                                      const float* __restrict__ w,
                                                      ushort* __restrict__ out) {
  int row = blockIdx.x;
  int tid = threadIdx.x;
  const float* xr = x + (size_t)row * DIM;
  float vals[16];
  float s = 0.f;
#pragma unroll
  for (int c = 0; c < 4; c++) {
    float4 v = *(const float4*)&xr[(tid + c * 256) * 4];
    vals[c * 4 + 0] = v.x; vals[c * 4 + 1] = v.y;
    vals[c * 4 + 2] = v.z; vals[c * 4 + 3] = v.w;
    s += v.x * v.x + v.y * v.y + v.z * v.z + v.w * v.w;
  }
#pragma unroll
  for (int off = 32; off >= 1; off >>= 1) s += __shfl_down(s, off);
  __shared__ float wsum[4];
  __shared__ float scale_s;
  int lane = tid & 63, wv = tid >> 6;
  if (lane == 0) wsum[wv] = s;
  __syncthreads();
  if (tid == 0) {
    float t = wsum[0] + wsum[1] + wsum[2] + wsum[3];
    scale_s = rsqrtf(t / (float)DIM + 1e-5f);
  }
  __syncthreads();
  float scale = scale_s;
  ushort* orow = out + (size_t)row * DIM;
#pragma unroll
  for (int c = 0; c < 4; c++) {
    int base = (tid + c * 256) * 4;
    float4 wv4 = *(const float4*)&w[base];
    ushort4v ov;
    ov.x = f2bf(vals[c * 4 + 0] * scale * wv4.x);
    ov.y = f2bf(vals[c * 4 + 1] * scale * wv4.y);
    ov.z = f2bf(vals[c * 4 + 2] * scale * wv4.z);
    ov.w = f2bf(vals[c * 4 + 3] * scale * wv4.w);
    *(ushort4v*)&orow[base] = ov;
  }
}

// ---------------- LoRA A: tbf[M][16] = A(bf16 M x K) @ la(K x 16), bf16 out ----------------
__global__ __launch_bounds__(256) void lora_a_kernel(const ushort* __restrict__ A,
                                                     const float* __restrict__ la,
                                                     ushort* __restrict__ tbf, int K) {
  int m = blockIdx.x, i = threadIdx.x;
  float acc[16];
#pragma unroll
  for (int n = 0; n < 16; n++) acc[n] = 0.f;
  for (int base = i * 16; base < K; base += 256 * 16) {
    bf16x8 a0 = *(const bf16x8*)&A[(size_t)m * K + base];
    bf16x8 a1 = *(const bf16x8*)&A[(size_t)m * K + base + 8];
    const float* lp = la + (size_t)base * LR;
#pragma unroll
    for (int kk = 0; kk < 16; kk++) {
      float av = bf2f((ushort)(kk < 8 ? a0[kk] : a1[kk - 8]));
#pragma unroll
      for (int n = 0; n < 16; n += 4) {
        float4 l = *(const float4*)&lp[kk * LR + n];
        acc[n] += av * l.x; acc[n + 1] += av * l.y;
        acc[n + 2] += av * l.z; acc[n + 3] += av * l.w;
      }
    }
  }
  __shared__ float red[256][16];
  __shared__ float red2[16][16];
#pragma unroll
  for (int n = 0; n < 16; n++) red[i][n] = acc[n];
  __syncthreads();
  {
    int g = i >> 4, n = i & 15;
    float s = 0.f;
#pragma unroll
    for (int j = 0; j < 16; j++) s += red[g * 16 + j][n];
    red2[g][n] = s;
  }
  __syncthreads();
  if (i < 16) {
    float s = 0.f;
#pragma unroll
    for (int g = 0; g < 16; g++) s += red2[g][i];
    tbf[(size_t)m * LR + i] = f2bf(s);
  }
}

// ================= 256x256 GEMM, 8 waves, dbuf + counted vmcnt + XOR swizzle =================
// out = A(M x K) @ W(N x K)^T  [+ lora K-ext when blockIdx.z==0]
// WM 0: bf16 direct [M][N];  WM 3: f32 partial slice [z][M][N]
template <int WM>
__global__ __launch_bounds__(512) void gemm256_kernel(
    const ushort* __restrict__ A, const ushort* __restrict__ W,
    const float* __restrict__ lb, const ushort* __restrict__ tbf,
    void* __restrict__ outp, int M, int N, int K, int nkp) {
  __shared__ __align__(16) ushort As[2][256 * 64];
  __shared__ __align__(16) ushort Bs[2][256 * 64];
  int tid = threadIdx.x;
  int lane = tid & 63, wave = tid >> 6;
  int wm = wave >> 2, wn = wave & 3;
  int n0 = blockIdx.x * 256, m0 = blockIdx.y * 256;
  int z = blockIdx.z;
  int k0 = z * nkp;  // K-tile offset

  // staging: issue i covers rows [i*64,+64); thread t -> row i*64 + (t>>3), slot t&7.
  // LDS dest linear in lane (wave-uniform base + lane*16B); source col pre-swizzled.
  int srow = tid >> 3;
  int sswz = ((tid & 7) ^ (srow & 7)) * 8;
  const ushort* Ab = A + (size_t)(m0 + srow) * K + sswz;
  const ushort* Wb = W + (size_t)(n0 + srow) * K + sswz;

  f32x4 acc[8][4] = {};

#define STAGE256(kt, b)                                                       \
  {                                                                           \
    ushort* pa = &As[b][wave * 8 * 64];                                       \
    ushort* pb = &Bs[b][wave * 8 * 64];                                       \
    const ushort* ga = Ab + (size_t)(kt) * 64;                                \
    const ushort* gb = Wb + (size_t)(kt) * 64;                                \
    _Pragma("unroll") for (int i = 0; i < 4; i++) {                           \
      gload_lds16(ga + (size_t)(i * 64) * K, pa + i * 64 * 64);               \
      gload_lds16(gb + (size_t)(i * 64) * K, pb + i * 64 * 64);               \
    }                                                                         \
  }

  STAGE256(k0, 0);
  for (int kk = 0; kk < nkp; kk++) {
    int cur = kk & 1;
    if (kk + 1 < nkp) {
      STAGE256(k0 + kk + 1, cur ^ 1);
      asm volatile("s_waitcnt vmcnt(8)" ::: "memory");  // drain tile kk, keep kk+1 in flight
    } else {
      asm volatile("s_waitcnt vmcnt(0)" ::: "memory");
    }
    __builtin_amdgcn_s_barrier();
    __builtin_amdgcn_sched_barrier(0);
    const ushort* as = As[cur];
    const ushort* bs = Bs[cur];
#pragma unroll
    for (int ks = 0; ks < 2; ks++) {
      bf16x8 af[8], bfr[4];
#pragma unroll
      for (int f = 0; f < 8; f++) {
        int ra = wm * 128 + f * 16 + (lane & 15);
        int sl = (ks * 4 + (lane >> 4)) ^ (ra & 7);
        af[f] = *(const bf16x8*)&as[ra * 64 + sl * 8];
      }
#pragma unroll
      for (int f = 0; f < 4; f++) {
        int rb = wn * 64 + f * 16 + (lane & 15);
        int sl = (ks * 4 + (lane >> 4)) ^ (rb & 7);
        bfr[f] = *(const bf16x8*)&bs[rb * 64 + sl * 8];
      }
      __builtin_amdgcn_s_setprio(1);
#pragma unroll
      for (int fm = 0; fm < 8; fm++)
#pragma unroll
        for (int fn = 0; fn < 4; fn++)
          acc[fm][fn] = __builtin_amdgcn_mfma_f32_16x16x32_bf16(af[fm], bfr[fn], acc[fm][fn], 0, 0, 0);
      __builtin_amdgcn_s_setprio(0);
    }
    asm volatile("" ::: "memory");
    __builtin_amdgcn_s_barrier();
    __builtin_amdgcn_sched_barrier(0);
  }
#undef STAGE256

  // ---- LoRA K-extension (split 0 only): K=32 slice, A=[t|0], B=[lb^T|0] ----
  if (z == 0) {
#pragma unroll
    for (int it = 0; it < 2; it++) {
      int task = tid + it * 512;  // 0..1023 = 256 rows x 4 slots
      int r = task >> 2, ls = task & 3;
      int ph = ls ^ (r & 7);
      bf16x8 avv = {};
      bf16x8 bvv = {};
      if (ls < 2) {
        avv = *(const bf16x8*)&tbf[(size_t)(m0 + r) * LR + ls * 8];
#pragma unroll
        for (int j = 0; j < 8; j++)
          bvv[j] = (short)f2bf(lb[(size_t)(ls * 8 + j) * N + n0 + r]);
      }
      *(bf16x8*)&As[0][r * 64 + ph * 8] = avv;
      *(bf16x8*)&Bs[0][r * 64 + ph * 8] = bvv;
    }
    __syncthreads();
    bf16x8 af[8], bfr[4];
#pragma unroll
    for (int f = 0; f < 8; f++) {
      int ra = wm * 128 + f * 16 + (lane & 15);
      int sl = (lane >> 4) ^ (ra & 7);
      af[f] = *(const bf16x8*)&As[0][ra * 64 + sl * 8];
    }
#pragma unroll
    for (int f = 0; f < 4; f++) {
      int rb = wn * 64 + f * 16 + (lane & 15);
      int sl = (lane >> 4) ^ (rb & 7);
      bfr[f] = *(const bf16x8*)&Bs[0][rb * 64 + sl * 8];
    }
#pragma unroll
    for (int fm = 0; fm < 8; fm++)
#pragma unroll
      for (int fn = 0; fn < 4; fn++)
        acc[fm][fn] = __builtin_amdgcn_mfma_f32_16x16x32_bf16(af[fm], bfr[fn], acc[fm][fn], 0, 0, 0);
  }

  // ---- write ----
#pragma unroll
  for (int fm = 0; fm < 8; fm++) {
#pragma unroll
    for (int j = 0; j < 4; j++) {
      int mg = m0 + wm * 128 + fm * 16 + (lane >> 4) * 4 + j;
#pragma unroll
      for (int fn = 0; fn < 4; fn++) {
        int ng = n0 + wn * 64 + fn * 16 + (lane & 15);
        float v = acc[fm][fn][j];
        if (WM == 0) {
          ((ushort*)outp)[(size_t)mg * N + ng] = f2bf(v);
        } else {
          ((float*)outp)[((size_t)z * M + mg) * (size_t)N + ng] = v;
        }
      }
    }
  }
}

// ---------------- split-K reduces ----------------
__global__ __launch_bounds__(256) void reduce4_bf16_kernel(const float* __restrict__ p,
                                                           ushort* __restrict__ out,
                                                           size_t sstride) {
  size_t i = ((size_t)blockIdx.x * 256 + threadIdx.x) * 4;
  float4 a = *(const float4*)&p[i];
  float4 b = *(const float4*)&p[i + sstride];
  float4 c = *(const float4*)&p[i + 2 * sstride];
  float4 d = *(const float4*)&p[i + 3 * sstride];
  ushort4v o;
  o.x = f2bf(a.x + b.x + c.x + d.x);
  o.y = f2bf(a.y + b.y + c.y + d.y);
  o.z = f2bf(a.z + b.z + c.z + d.z);
  o.w = f2bf(a.w + b.w + c.w + d.w);
  *(ushort4v*)&out[i] = o;
}

__global__ __launch_bounds__(256) void reduce4_res_kernel(const float* __restrict__ p,
                                                          const float* __restrict__ res,
                                                          float* __restrict__ out,
                                                          size_t sstride) {
  size_t i = ((size_t)blockIdx.x * 256 + threadIdx.x) * 4;
  float4 a = *(const float4*)&p[i];
  float4 b = *(const float4*)&p[i + sstride];
  float4 c = *(const float4*)&p[i + 2 * sstride];
  float4 d = *(const float4*)&p[i + 3 * sstride];
  float4 r = *(const float4*)&res[i];
  float4 o;
  o.x = a.x + b.x + c.x + d.x + r.x;
  o.y = a.y + b.y + c.y + d.y + r.y;
  o.z = a.z + b.z + c.z + d.z + r.z;
  o.w = a.w + b.w + c.w + d.w + r.w;
  *(float4*)&out[i] = o;
}

#define BM 128
#define BN 128
#define BK 64

// ---------------- 128x128 bf16 GEMM (for small-N: wk, wv) ----------------
// MODE 0: bf16 out [M][N];  MODE 1: bf16 out transposed [N][M]
template <int MODE>
__global__ __launch_bounds__(256) void gemm_bf16_db(
    const ushort* __restrict__ A, const ushort* __restrict__ W,
    const float* __restrict__ lb, const ushort* __restrict__ tbf,
    const float* __restrict__ res, void* __restrict__ outp,
    int M, int N, int K) {
  __shared__ __align__(16) ushort As[2][BM * BK];
  __shared__ __align__(16) ushort Bs[2][BN * BK];
  int tid = threadIdx.x;
  int lane = tid & 63, wave = tid >> 6;
  int wr = wave >> 1, wc = wave & 1;
  int m0 = blockIdx.y * BM, n0 = blockIdx.x * BN;

  int lr = lane >> 3;
  int swz = ((lane & 7) ^ lr) * 8;
  const ushort* Ab = A + (size_t)(m0 + wave * 8 + lr) * K + swz;
  const ushort* Wb = W + (size_t)(n0 + wave * 8 + lr) * K + swz;

  f32x4 acc[4][4] = {};
  int nk = K / BK;

#define STAGE(kt, b)                                                      \
  {                                                                       \
    ushort* pa = &As[b][wave * 8 * BK];                                   \
    ushort* pb = &Bs[b][wave * 8 * BK];                                   \
    const ushort* ga = Ab + (kt) * BK;                                    \
    const ushort* gb = Wb + (kt) * BK;                                    \
    _Pragma("unroll") for (int i = 0; i < 4; i++) {                       \
      gload_lds16(ga + (size_t)(i * 32) * K, pa + i * 32 * BK);           \
      gload_lds16(gb + (size_t)(i * 32) * K, pb + i * 32 * BK);           \
    }                                                                     \
  }

  STAGE(0, 0);
  for (int kt = 0; kt < nk; kt++) {
    int cur = kt & 1;
    if (kt + 1 < nk) {
      STAGE(kt + 1, cur ^ 1);
      asm volatile("s_waitcnt vmcnt(8)" ::: "memory");
    } else {
      asm volatile("s_waitcnt vmcnt(0)" ::: "memory");
    }
    __builtin_amdgcn_s_barrier();
    __builtin_amdgcn_sched_barrier(0);
    const ushort* as = As[cur];
    const ushort* bs = Bs[cur];
#pragma unroll
    for (int ks = 0; ks < 2; ks++) {
      bf16x8 af[4], bfr[4];
#pragma unroll
      for (int f = 0; f < 4; f++) {
        int ra = wr * 64 + f * 16 + (lane & 15);
        int rb = wc * 64 + f * 16 + (lane & 15);
        int sl = (ks * 4 + (lane >> 4)) ^ (lane & 7);
        af[f] = *(const bf16x8*)&as[ra * BK + ((ks * 4 + (lane >> 4)) ^ (ra & 7)) * 8];
        bfr[f] = *(const bf16x8*)&bs[rb * BK + ((ks * 4 + (lane >> 4)) ^ (rb & 7)) * 8];
        (void)sl;
      }
#pragma unroll
      for (int fm = 0; fm < 4; fm++)
#pragma unroll
        for (int fn = 0; fn < 4; fn++)
          acc[fm][fn] = __builtin_amdgcn_mfma_f32_16x16x32_bf16(af[fm], bfr[fn], acc[fm][fn], 0, 0, 0);
    }
    asm volatile("" ::: "memory");
    __builtin_amdgcn_s_barrier();
    __builtin_amdgcn_sched_barrier(0);
  }
#undef STAGE

  // lora K-extension
  for (int task = tid; task < 512; task += 256) {
    int r = task >> 2, ls = task & 3;
    int ph = ls ^ (r & 7);
    bf16x8 avv = {};
    bf16x8 bvv = {};
    if (ls < 2) {
      avv = *(const bf16x8*)&tbf[(size_t)(m0 + r) * LR + ls * 8];
#pragma unroll
      for (int j = 0; j < 8; j++)
        bvv[j] = (short)f2bf(lb[(size_t)(ls * 8 + j) * N + n0 + r]);
    }
    *(bf16x8*)&As[0][r * BK + ph * 8] = avv;
    *(bf16x8*)&Bs[0][r * BK + ph * 8] = bvv;
  }
  __syncthreads();
  {
    bf16x8 af[4], bfr[4];
#pragma unroll
    for (int f = 0; f < 4; f++) {
      int ra = wr * 64 + f * 16 + (lane & 15);
      int rb = wc * 64 + f * 16 + (lane & 15);
      af[f] = *(const bf16x8*)&As[0][ra * BK + ((lane >> 4) ^ (ra & 7)) * 8];
      bfr[f] = *(const bf16x8*)&Bs[0][rb * BK + ((lane >> 4) ^ (rb & 7)) * 8];
    }
#pragma unroll
    for (int fm = 0; fm < 4; fm++)
#pragma unroll
      for (int fn = 0; fn < 4; fn++)
        acc[fm][fn] = __builtin_amdgcn_mfma_f32_16x16x32_bf16(af[fm], bfr[fn], acc[fm][fn], 0, 0, 0);
  }

#pragma unroll
  for (int fm = 0; fm < 4; fm++) {
#pragma unroll
    for (int j = 0; j < 4; j++) {
      int mg = m0 + wr * 64 + fm * 16 + (lane >> 4) * 4 + j;
#pragma unroll
      for (int fn = 0; fn < 4; fn++) {
        int ng = n0 + wc * 64 + fn * 16 + (lane & 15);
        float v = acc[fm][fn][j];
        if (MODE == 0) {
          ((ushort*)outp)[(size_t)mg * N + ng] = f2bf(v);
        } else {
          ((ushort*)outp)[(size_t)ng * M + mg] = f2bf(v);
        }
      }
    }
  }
}

// ---------------- RoPE (in-place, bf16), rotate_half, optional scale ----------------
__global__ __launch_bounds__(256) void rope_kernel(ushort* __restrict__ x,
                                                   const float* __restrict__ ct,
                                                   const float* __restrict__ st,
                                                   int nheads, float scale) {
  int idx = blockIdx.x * 256 + threadIdx.x;
  int d = idx & 63;
  int hh = (idx >> 6) % nheads;
  int s = idx / (64 * nheads);
  ushort* p = x + (size_t)s * (nheads * HD) + hh * HD + d;
  float x1 = bf2f(p[0]), x2 = bf2f(p[64]);
  float c = ct[s * HD + d], sn = st[s * HD + d];
  p[0] = f2bf((x1 * c - x2 * sn) * scale);
  p[64] = f2bf((x2 * c + x1 * sn) * scale);
}

// ---------------- Flash attention (causal, GQA 4:1) ----------------
__global__ __launch_bounds__(256) void attn_kernel(const ushort* __restrict__ q,
                                                   const ushort* __restrict__ k,
                                                   const ushort* __restrict__ vt,
                                                   ushort* __restrict__ o) {
  int qb = blockIdx.x, h = blockIdx.y, kvh = h >> 2;
  int tid = threadIdx.x, lane = tid & 63, wave = tid >> 6;
  __shared__ ushort Ks[64][136];
  __shared__ ushort Vs[128][72];
  __shared__ ushort Ps[4][16][72];

  bf16x8 qf[4];
  int qrow = qb * 64 + wave * 16 + (lane & 15);
#pragma unroll
  for (int kk = 0; kk < 4; kk++)
    qf[kk] = *(const bf16x8*)&q[(size_t)qrow * DIM + h * HD + kk * 32 + (lane >> 4) * 8];

  f32x4 oacc[8] = {};
  float mrow[4], lrow[4];
  int qr[4];
#pragma unroll
  for (int j = 0; j < 4; j++) {
    mrow[j] = -INFINITY; lrow[j] = 0.f;
    qr[j] = qb * 64 + wave * 16 + (lane >> 4) * 4 + j;
  }

  for (int kt = 0; kt <= qb; kt++) {
    int key0 = kt * 64;
#pragma unroll
    for (int c = 0; c < 4; c++) {
      int e = tid * 32 + c * 8;
      int r = e >> 7, cc = e & 127;
      *(bf16x8*)&Ks[r][cc] =
          *(const bf16x8*)&k[(size_t)(key0 + r) * (NKVH * HD) + kvh * HD + cc];
      int r2 = e >> 6, cc2 = e & 63;
      *(bf16x8*)&Vs[r2][cc2] =
          *(const bf16x8*)&vt[(size_t)(kvh * HD + r2) * SEQ + key0 + cc2];
    }
    __syncthreads();

    f32x4 sf[4] = {};
#pragma unroll
    for (int fn = 0; fn < 4; fn++)
#pragma unroll
      for (int kk = 0; kk < 4; kk++) {
        bf16x8 kf = *(const bf16x8*)&Ks[fn * 16 + (lane & 15)][kk * 32 + (lane >> 4) * 8];
        sf[fn] = __builtin_amdgcn_mfma_f32_16x16x32_bf16(qf[kk], kf, sf[fn], 0, 0, 0);
      }

#pragma unroll
    for (int fn = 0; fn < 4; fn++) {
      int key = key0 + fn * 16 + (lane & 15);
#pragma unroll
      for (int j = 0; j < 4; j++)
        if (key > qr[j]) sf[fn][j] = -INFINITY;
    }

#pragma unroll
    for (int j = 0; j < 4; j++) {
      float mx = fmaxf(fmaxf(sf[0][j], sf[1][j]), fmaxf(sf[2][j], sf[3][j]));
#pragma unroll
      for (int off = 1; off < 16; off <<= 1) mx = fmaxf(mx, __shfl_xor(mx, off));
      float mnew = fmaxf(mrow[j], mx);
      float sc = __expf(mrow[j] - mnew);
      mrow[j] = mnew;
      float rs = 0.f;
#pragma unroll
      for (int fn = 0; fn < 4; fn++) {
        float p = __expf(sf[fn][j] - mnew);
        sf[fn][j] = p;
        rs += p;
      }
#pragma unroll
      for (int off = 1; off < 16; off <<= 1) rs += __shfl_xor(rs, off);
      lrow[j] = lrow[j] * sc + rs;
#pragma unroll
      for (int f2 = 0; f2 < 8; f2++) oacc[f2][j] *= sc;
    }

#pragma unroll
    for (int fn = 0; fn < 4; fn++)
#pragma unroll
      for (int j = 0; j < 4; j++)
        Ps[wave][(lane >> 4) * 4 + j][fn * 16 + (lane & 15)] = f2bf(sf[fn][j]);

#pragma unroll
    for (int kk = 0; kk < 2; kk++) {
      bf16x8 pf = *(const bf16x8*)&Ps[wave][lane & 15][kk * 32 + (lane >> 4) * 8];
#pragma unroll
      for (int f2 = 0; f2 < 8; f2++) {
        bf16x8 vf = *(const bf16x8*)&Vs[f2 * 16 + (lane & 15)][kk * 32 + (lane >> 4) * 8];
        oacc[f2] = __builtin_amdgcn_mfma_f32_16x16x32_bf16(pf, vf, oacc[f2], 0, 0, 0);
      }
    }
    __syncthreads();
  }

#pragma unroll
  for (int j = 0; j < 4; j++) {
    float inv = 1.f / lrow[j];
#pragma unroll
    for (int f2 = 0; f2 < 8; f2++)
      o[(size_t)qr[j] * DIM + h * HD + f2 * 16 + (lane & 15)] = f2bf(oacc[f2][j] * inv);
  }
}

// ---------------- h = silu(gate) * up ----------------
__global__ __launch_bounds__(256) void silu_mul_kernel(const ushort* __restrict__ g,
                                                       const ushort* __restrict__ u,
                                                       ushort* __restrict__ h) {
  size_t idx = (size_t)(blockIdx.x * 256 + threadIdx.x) * 8;
  bf16x8 gv = *(const bf16x8*)&g[idx];
  bf16x8 uv = *(const bf16x8*)&u[idx];
  bf16x8 hv;
#pragma unroll
  for (int i = 0; i < 8; i++) {
    float gf = bf2f((ushort)gv[i]);
    float uf = bf2f((ushort)uv[i]);
    float sv = gf / (1.f + __expf(-gf));
    hv[i] = (short)f2bf(sv * uf);
  }
  *(bf16x8*)&h[idx] = hv;
}

extern "C" void kernel_launch(void* const* d_in, const int* in_sizes, int n_in,
                              void* d_out, int out_size, void* d_ws, size_t ws_size,
                              hipStream_t stream) {
  const float* x    = (const float*)d_in[0];
  const float* w1   = (const float*)d_in[1];
  const float* w2   = (const float*)d_in[2];
  const float* cosT = (const float*)d_in[3];
  const float* sinT = (const float*)d_in[4];
  const float* wq = (const float*)d_in[6];
  const float* la_q = (const float*)d_in[7];
  const float* lb_q = (const float*)d_in[8];
  const float* wk = (const float*)d_in[9];
  const float* la_k = (const float*)d_in[10];
  const float* lb_k = (const float*)d_in[11];
  const float* wv = (const float*)d_in[12];
  const float* la_v = (const float*)d_in[13];
  const float* lb_v = (const float*)d_in[14];
  const float* wo = (const float*)d_in[15];
  const float* la_o = (const float*)d_in[16];
  const float* lb_o = (const float*)d_in[17];
  const float* wg = (const float*)d_in[18];
  const float* la_g = (const float*)d_in[19];
  const float* lb_g = (const float*)d_in[20];
  const float* wu = (const float*)d_in[21];
  const float* la_u = (const float*)d_in[22];
  const float* lb_u = (const float*)d_in[23];
  const float* wd = (const float*)d_in[24];
  const float* la_d = (const float*)d_in[25];
  const float* lb_d = (const float*)d_in[26];
  float* out = (float*)d_out;

  char* ws = (char*)d_ws;
  ushort* xn1 = (ushort*)ws;  ws += (size_t)SEQ * DIM * 2;   // 8 MB
  ushort* qb  = (ushort*)ws;  ws += (size_t)SEQ * DIM * 2;   // 8 MB
  ushort* kb  = (ushort*)ws;  ws += (size_t)SEQ * NKVH * HD * 2;
  ushort* vtb = (ushort*)ws;  ws += (size_t)SEQ * NKVH * HD * 2;
  ushort* ob  = (ushort*)ws;  ws += (size_t)SEQ * DIM * 2;
  float*  xmed= (float*)ws;   ws += (size_t)SEQ * DIM * 4;   // 16 MB
  ushort* xn2 = (ushort*)ws;  ws += (size_t)SEQ * DIM * 2;   // 8 MB
  ushort* gate= (ushort*)ws;  ws += (size_t)SEQ * FF * 2;    // 28 MB
  ushort* up  = (ushort*)ws;  ws += (size_t)SEQ * FF * 2;    // 28 MB
  ushort* hb  = (ushort*)ws;  ws += (size_t)SEQ * FF * 2;    // 28 MB
  ushort* t_q = (ushort*)ws; ws += SEQ * LR * 2;
  ushort* t_k = (ushort*)ws; ws += SEQ * LR * 2;
  ushort* t_v = (ushort*)ws; ws += SEQ * LR * 2;
  ushort* t_o = (ushort*)ws; ws += SEQ * LR * 2;
  ushort* t_g = (ushort*)ws; ws += SEQ * LR * 2;
  ushort* t_u = (ushort*)ws; ws += SEQ * LR * 2;
  ushort* t_d = (ushort*)ws; ws += SEQ * LR * 2;
  ushort* wbf = (ushort*)ws; ws += (size_t)FF * DIM * 2;     // 112 MB rotating bf16 weights

  // split-K partial buffers aliased onto dead regions (4 x M x N f32 = 64 MB):
  float* pbuf1 = (float*)gate;  // wq / wo partials: gate+up+hb dead then (84 MB)
  float* pbuf2 = (float*)xn2;   // wd partials: xn2+gate+up dead then (exactly 64 MB)

  size_t snd = (size_t)SEQ * DIM;  // split stride

  auto cvt = [&](const float* w, size_t n) {
    w_convert_kernel<<<2048, 256, 0, stream>>>(w, wbf, n / 8);
  };

  // 1) xn1 = rms(x) * w1
  rmsnorm_kernel<<<SEQ, 256, 0, stream>>>(x, w1, xn1);
  lora_a_kernel<<<SEQ, 256, 0, stream>>>(xn1, la_q, t_q, DIM);
  lora_a_kernel<<<SEQ, 256, 0, stream>>>(xn1, la_k, t_k, DIM);
  lora_a_kernel<<<SEQ, 256, 0, stream>>>(xn1, la_v, t_v, DIM);

  // 2) Q (256^2 split-K4), K/V (128^2)
  cvt(wq, (size_t)DIM * DIM);
  gemm256_kernel<3><<<dim3(DIM / 256, SEQ / 256, 4), 512, 0, stream>>>(
      xn1, wbf, lb_q, t_q, pbuf1, SEQ, DIM, DIM, 16);
  reduce4_bf16_kernel<<<snd / 1024, 256, 0, stream>>>(pbuf1, qb, snd);
  cvt(wk, (size_t)NKVH * HD * DIM);
  gemm_bf16_db<0><<<dim3(NKVH * HD / BN, SEQ / BM), 256, 0, stream>>>(
      xn1, wbf, lb_k, t_k, nullptr, kb, SEQ, NKVH * HD, DIM);
  cvt(wv, (size_t)NKVH * HD * DIM);
  gemm_bf16_db<1><<<dim3(NKVH * HD / BN, SEQ / BM), 256, 0, stream>>>(
      xn1, wbf, lb_v, t_v, nullptr, vtb, SEQ, NKVH * HD, DIM);

  // 3) RoPE (q pre-scaled by 1/sqrt(HD)) + attention
  rope_kernel<<<SEQ * NH * 64 / 256, 256, 0, stream>>>(qb, cosT, sinT, NH, 0.08838834764831845f);
  rope_kernel<<<SEQ * NKVH * 64 / 256, 256, 0, stream>>>(kb, cosT, sinT, NKVH, 1.0f);
  attn_kernel<<<dim3(SEQ / 64, NH), 256, 0, stream>>>(qb, kb, vtb, ob);

  // 4) WO (split-K4) + residual -> xmed
  lora_a_kernel<<<SEQ, 256, 0, stream>>>(ob, la_o, t_o, DIM);
  cvt(wo, (size_t)DIM * DIM);
  gemm256_kernel<3><<<dim3(DIM / 256, SEQ / 256, 4), 512, 0, stream>>>(
      ob, wbf, lb_o, t_o, pbuf1, SEQ, DIM, DIM, 16);
  reduce4_res_kernel<<<snd / 1024, 256, 0, stream>>>(pbuf1, x, xmed, snd);

  // 5) FFN
  rmsnorm_kernel<<<SEQ, 256, 0, stream>>>(xmed, w2, xn2);
  lora_a_kernel<<<SEQ, 256, 0, stream>>>(xn2, la_g, t_g, DIM);
  lora_a_kernel<<<SEQ, 256, 0, stream>>>(xn2, la_u, t_u, DIM);
  cvt(wg, (size_t)FF * DIM);
  gemm256_kernel<0><<<dim3(FF / 256, SEQ / 256, 1), 512, 0, stream>>>(
      xn2, wbf, lb_g, t_g, gate, SEQ, FF, DIM, DIM / 64);
  cvt(wu, (size_t)FF * DIM);
  gemm256_kernel<0><<<dim3(FF / 256, SEQ / 256, 1), 512, 0, stream>>>(
      xn2, wbf, lb_u, t_u, up, SEQ, FF, DIM, DIM / 64);
  silu_mul_kernel<<<SEQ * FF / 8 / 256, 256, 0, stream>>>(gate, up, hb);
  lora_a_kernel<<<SEQ, 256, 0, stream>>>(hb, la_d, t_d, FF);
  cvt(wd, (size_t)DIM * FF);
  gemm256_kernel<3><<<dim3(DIM / 256, SEQ / 256, 4), 512, 0, stream>>>(
      hb, wbf, lb_d, t_d, pbuf2, SEQ, DIM, FF, FF / 4 / 64);
  reduce4_res_kernel<<<snd / 1024, 256, 0, stream>>>(pbuf2, xmed, out, snd);
}

// Round 5
// 1392.349 us; speedup vs baseline: 2.2221x; 1.0541x over previous
//
#include <hip/hip_runtime.h>
#include <hip/hip_bf16.h>
#include <math.h>

#define SEQ 1024
#define DIM 4096
#define NH 32
#define HD 128
#define NKVH 8
#define FF 14336
#define LR 16

typedef __attribute__((ext_vector_type(8))) short bf16x8;
typedef __attribute__((ext_vector_type(4))) float f32x4;
typedef __attribute__((ext_vector_type(4))) ushort ushort4v;

__device__ __forceinline__ ushort f2bf(float f) {
  union { float f; unsigned u; } v; v.f = f;
  unsigned r = (v.u + 0x7FFFu + ((v.u >> 16) & 1u)) >> 16;
  return (ushort)r;
}
__device__ __forceinline__ float bf2f(ushort h) {
  union { unsigned u; float f; } v; v.u = ((unsigned)h) << 16;
  return v.f;
}

__device__ __forceinline__ void gload_lds16(const void* g, void* l) {
  __builtin_amdgcn_global_load_lds(
      (const __attribute__((address_space(1))) void*)g,
      (__attribute__((address_space(3))) void*)l, 16, 0, 0);
}

// ---------------- weight f32 -> bf16 convert (grid-stride) ----------------
__global__ __launch_bounds__(256) void w_convert_kernel(const float* __restrict__ in,
                                                        ushort* __restrict__ out,
                                                        size_t n8) {
  size_t stride = (size_t)gridDim.x * 256;
  for (size_t i = (size_t)blockIdx.x * 256 + threadIdx.x; i < n8; i += stride) {
    size_t b = i * 8;
    float4 a = *(const float4*)&in[b];
    float4 c = *(const float4*)&in[b + 4];
    bf16x8 o;
    o[0] = (short)f2bf(a.x); o[1] = (short)f2bf(a.y);
    o[2] = (short)f2bf(a.z); o[3] = (short)f2bf(a.w);
    o[4] = (short)f2bf(c.x); o[5] = (short)f2bf(c.y);
    o[6] = (short)f2bf(c.z); o[7] = (short)f2bf(c.w);
    *(bf16x8*)&out[b] = o;
  }
}

// ---------------- RMSNorm: f32 in -> bf16 out ----------------
__global__ __launch_bounds__(256) void rmsnorm_kernel(const float* __restrict__ x,
                                                      const float* __restrict__ w,
                                                      ushort* __restrict__ out) {
  int row = blockIdx.x;
  int tid = threadIdx.x;
  const float* xr = x + (size_t)row * DIM;
  float vals[16];
  float s = 0.f;
#pragma unroll
  for (int c = 0; c < 4; c++) {
    float4 v = *(const float4*)&xr[(tid + c * 256) * 4];
    vals[c * 4 + 0] = v.x; vals[c * 4 + 1] = v.y;
    vals[c * 4 + 2] = v.z; vals[c * 4 + 3] = v.w;
    s += v.x * v.x + v.y * v.y + v.z * v.z + v.w * v.w;
  }
#pragma unroll
  for (int off = 32; off >= 1; off >>= 1) s += __shfl_down(s, off);
  __shared__ float wsum[4];
  __shared__ float scale_s;
  int lane = tid & 63, wv = tid >> 6;
  if (lane == 0) wsum[wv] = s;
  __syncthreads();
  if (tid == 0) {
    float t = wsum[0] + wsum[1] + wsum[2] + wsum[3];
    scale_s = rsqrtf(t / (float)DIM + 1e-5f);
  }
  __syncthreads();
  float scale = scale_s;
  ushort* orow = out + (size_t)row * DIM;
#pragma unroll
  for (int c = 0; c < 4; c++) {
    int base = (tid + c * 256) * 4;
    float4 wv4 = *(const float4*)&w[base];
    ushort4v ov;
    ov.x = f2bf(vals[c * 4 + 0] * scale * wv4.x);
    ov.y = f2bf(vals[c * 4 + 1] * scale * wv4.y);
    ov.z = f2bf(vals[c * 4 + 2] * scale * wv4.z);
    ov.w = f2bf(vals[c * 4 + 3] * scale * wv4.w);
    *(ushort4v*)&orow[base] = ov;
  }
}

// ---------------- LoRA A: tbf[M][16] = A(bf16 M x K) @ la(K x 16), bf16 out ----------------
__global__ __launch_bounds__(256) void lora_a_kernel(const ushort* __restrict__ A,
                                                     const float* __restrict__ la,
                                                     ushort* __restrict__ tbf, int K) {
  int m = blockIdx.x, i = threadIdx.x;
  float acc[16];
#pragma unroll
  for (int n = 0; n < 16; n++) acc[n] = 0.f;
  for (int base = i * 16; base < K; base += 256 * 16) {
    bf16x8 a0 = *(const bf16x8*)&A[(size_t)m * K + base];
    bf16x8 a1 = *(const bf16x8*)&A[(size_t)m * K + base + 8];
    const float* lp = la + (size_t)base * LR;
#pragma unroll
    for (int kk = 0; kk < 16; kk++) {
      float av = bf2f((ushort)(kk < 8 ? a0[kk] : a1[kk - 8]));
#pragma unroll
      for (int n = 0; n < 16; n += 4) {
        float4 l = *(const float4*)&lp[kk * LR + n];
        acc[n] += av * l.x; acc[n + 1] += av * l.y;
        acc[n + 2] += av * l.z; acc[n + 3] += av * l.w;
      }
    }
  }
  __shared__ float red[256][16];
  __shared__ float red2[16][16];
#pragma unroll
  for (int n = 0; n < 16; n++) red[i][n] = acc[n];
  __syncthreads();
  {
    int g = i >> 4, n = i & 15;
    float s = 0.f;
#pragma unroll
    for (int j = 0; j < 16; j++) s += red[g * 16 + j][n];
    red2[g][n] = s;
  }
  __syncthreads();
  if (i < 16) {
    float s = 0.f;
#pragma unroll
    for (int g = 0; g < 16; g++) s += red2[g][i];
    tbf[(size_t)m * LR + i] = f2bf(s);
  }
}

// ================= 256x256 GEMM, 8 waves, 4-phase/K-tile pipeline =================
// out = A(M x K) @ W(N x K)^T  [+ lora K-ext when blockIdx.z==0]
// lb/t segments: cols [0,c1) -> (lb0,t0,w=c1); [c1,c2) -> (lb1,t1,w=c2-c1); [c2,N) -> (lb2,t2)
// WM 0: bf16 direct [M][N];  WM 3: f32 partial slice [z][M][N]
template <int WM>
__global__ __launch_bounds__(512) void gemm256_kernel(
    const ushort* __restrict__ A, const ushort* __restrict__ W,
    const float* __restrict__ lb0, const float* __restrict__ lb1,
    const float* __restrict__ lb2, const ushort* __restrict__ t0,
    const ushort* __restrict__ t1, const ushort* __restrict__ t2,
    int c1, int c2, void* __restrict__ outp, int M, int N, int K, int nkp) {
  __shared__ __align__(16) ushort As[2][256 * 64];
  __shared__ __align__(16) ushort Bs[2][256 * 64];
  int tid = threadIdx.x;
  int lane = tid & 63, wave = tid >> 6;
  int wm = wave >> 2, wn = wave & 3;
  int n0 = blockIdx.x * 256, m0 = blockIdx.y * 256;
  int z = blockIdx.z;
  int k0 = z * nkp;

  // staging: issue p covers rows [p*64,+64); per-wave rows w*8+(lane>>3), slot lane&7
  int srow = tid >> 3;
  int sswz = ((tid & 7) ^ (srow & 7)) * 8;  // inverse-swizzled source col
  const ushort* Ab = A + (size_t)(m0 + srow) * K + sswz;
  const ushort* Wb = W + (size_t)(n0 + srow) * K + sswz;

  f32x4 acc[8][4] = {};

#define ISSUE2(kt, b, p)                                                      \
  {                                                                           \
    gload_lds16(Ab + (size_t)((p) * 64) * K + (size_t)(kt) * 64,              \
                &As[b][wave * 512 + (p) * 4096]);                             \
    gload_lds16(Wb + (size_t)((p) * 64) * K + (size_t)(kt) * 64,              \
                &Bs[b][wave * 512 + (p) * 4096]);                             \
  }
#define LDFRAG(buf, r, ks) \
  (*(const bf16x8*)&(buf)[(r) * 64 + (((ks) * 4 + (lane >> 4)) ^ ((r) & 7)) * 8])

  // prologue: stage tile k0 into buf 0
#pragma unroll
  for (int p = 0; p < 4; p++) ISSUE2(k0, 0, p);

  for (int t = 0; t < nkp; t++) {
    int cur = t & 1;
    asm volatile("s_waitcnt vmcnt(0)" ::: "memory");
    __builtin_amdgcn_s_barrier();
    __builtin_amdgcn_sched_barrier(0);
    const ushort* as = As[cur];
    const ushort* bs = Bs[cur];
    bool pre = (t + 1 < nkp);
    bf16x8 bfr[4][2];
#pragma unroll
    for (int p = 0; p < 4; p++) {
      bf16x8 af[2][2];
#pragma unroll
      for (int q = 0; q < 2; q++) {
        int ra = wm * 128 + (p * 2 + q) * 16 + (lane & 15);
#pragma unroll
        for (int ks = 0; ks < 2; ks++) af[q][ks] = LDFRAG(as, ra, ks);
      }
      if (p == 0) {
#pragma unroll
        for (int f = 0; f < 4; f++) {
          int rb = wn * 64 + f * 16 + (lane & 15);
#pragma unroll
          for (int ks = 0; ks < 2; ks++) bfr[f][ks] = LDFRAG(bs, rb, ks);
        }
      }
      if (pre) ISSUE2(k0 + t + 1, cur ^ 1, p);
      __builtin_amdgcn_sched_barrier(0);
      __builtin_amdgcn_s_barrier();
      asm volatile("s_waitcnt lgkmcnt(0)" ::: "memory");
      __builtin_amdgcn_sched_barrier(0);
      __builtin_amdgcn_s_setprio(1);
#pragma unroll
      for (int q = 0; q < 2; q++)
#pragma unroll
        for (int fn = 0; fn < 4; fn++)
#pragma unroll
          for (int ks = 0; ks < 2; ks++)
            acc[p * 2 + q][fn] = __builtin_amdgcn_mfma_f32_16x16x32_bf16(
                af[q][ks], bfr[fn][ks], acc[p * 2 + q][fn], 0, 0, 0);
      __builtin_amdgcn_s_setprio(0);
      __builtin_amdgcn_sched_barrier(0);
      __builtin_amdgcn_s_barrier();
    }
  }
#undef ISSUE2

  // ---- LoRA K-extension (split 0 only): K=32 slice, A=[t|0], B=[lb^T|0] ----
  if (z == 0) {
    const float* lbp;
    const ushort* tp;
    int wseg;
    if (n0 < c1) { lbp = lb0 + n0; tp = t0; wseg = c1; }
    else if (n0 < c2) { lbp = lb1 + (n0 - c1); tp = t1; wseg = c2 - c1; }
    else { lbp = lb2 + (n0 - c2); tp = t2; wseg = N - c2; }
#pragma unroll
    for (int it = 0; it < 2; it++) {
      int task = tid + it * 512;  // 256 rows x 4 slots
      int r = task >> 2, ls = task & 3;
      int ph = ls ^ (r & 7);
      bf16x8 avv = {};
      bf16x8 bvv = {};
      if (ls < 2) {
        avv = *(const bf16x8*)&tp[(size_t)(m0 + r) * LR + ls * 8];
#pragma unroll
        for (int j = 0; j < 8; j++)
          bvv[j] = (short)f2bf(lbp[(size_t)(ls * 8 + j) * wseg + r]);
      }
      *(bf16x8*)&As[0][r * 64 + ph * 8] = avv;
      *(bf16x8*)&Bs[0][r * 64 + ph * 8] = bvv;
    }
    __syncthreads();
    bf16x8 af[8], bfr[4];
#pragma unroll
    for (int f = 0; f < 8; f++) {
      int ra = wm * 128 + f * 16 + (lane & 15);
      af[f] = LDFRAG(As[0], ra, 0);
    }
#pragma unroll
    for (int f = 0; f < 4; f++) {
      int rb = wn * 64 + f * 16 + (lane & 15);
      bfr[f] = LDFRAG(Bs[0], rb, 0);
    }
#pragma unroll
    for (int fm = 0; fm < 8; fm++)
#pragma unroll
      for (int fn = 0; fn < 4; fn++)
        acc[fm][fn] = __builtin_amdgcn_mfma_f32_16x16x32_bf16(af[fm], bfr[fn], acc[fm][fn], 0, 0, 0);
  }
#undef LDFRAG

  // ---- write ----
#pragma unroll
  for (int fm = 0; fm < 8; fm++) {
#pragma unroll
    for (int j = 0; j < 4; j++) {
      int mg = m0 + wm * 128 + fm * 16 + (lane >> 4) * 4 + j;
#pragma unroll
      for (int fn = 0; fn < 4; fn++) {
        int ng = n0 + wn * 64 + fn * 16 + (lane & 15);
        float v = acc[fm][fn][j];
        if (WM == 0) {
          ((ushort*)outp)[(size_t)mg * N + ng] = f2bf(v);
        } else {
          ((float*)outp)[((size_t)z * M + mg) * (size_t)N + ng] = v;
        }
      }
    }
  }
}

// ---------------- split-K reduces ----------------
// QKV fused: p has 2 slices of [M][6144]; route cols to qb / kb / vt(transposed)
__global__ __launch_bounds__(256) void reduce2_qkv_kernel(const float* __restrict__ p,
                                                          ushort* __restrict__ qb,
                                                          ushort* __restrict__ kb,
                                                          ushort* __restrict__ vtb) {
  size_t i4 = ((size_t)blockIdx.x * 256 + threadIdx.x) * 4;
  size_t sstride = (size_t)SEQ * 6144;
  int m = (int)(i4 / 6144);
  int c = (int)(i4 % 6144);
  float4 a = *(const float4*)&p[i4];
  float4 b = *(const float4*)&p[i4 + sstride];
  float4 s;
  s.x = a.x + b.x; s.y = a.y + b.y; s.z = a.z + b.z; s.w = a.w + b.w;
  if (c < DIM) {
    ushort4v o;
    o.x = f2bf(s.x); o.y = f2bf(s.y); o.z = f2bf(s.z); o.w = f2bf(s.w);
    *(ushort4v*)&qb[(size_t)m * DIM + c] = o;
  } else if (c < DIM + 1024) {
    ushort4v o;
    o.x = f2bf(s.x); o.y = f2bf(s.y); o.z = f2bf(s.z); o.w = f2bf(s.w);
    *(ushort4v*)&kb[(size_t)m * 1024 + (c - DIM)] = o;
  } else {
    int n = c - DIM - 1024;
    vtb[(size_t)(n + 0) * SEQ + m] = f2bf(s.x);
    vtb[(size_t)(n + 1) * SEQ + m] = f2bf(s.y);
    vtb[(size_t)(n + 2) * SEQ + m] = f2bf(s.z);
    vtb[(size_t)(n + 3) * SEQ + m] = f2bf(s.w);
  }
}

__global__ __launch_bounds__(256) void reduce4_res_kernel(const float* __restrict__ p,
                                                          const float* __restrict__ res,
                                                          float* __restrict__ out,
                                                          size_t sstride) {
  size_t i = ((size_t)blockIdx.x * 256 + threadIdx.x) * 4;
  float4 a = *(const float4*)&p[i];
  float4 b = *(const float4*)&p[i + sstride];
  float4 c = *(const float4*)&p[i + 2 * sstride];
  float4 d = *(const float4*)&p[i + 3 * sstride];
  float4 r = *(const float4*)&res[i];
  float4 o;
  o.x = a.x + b.x + c.x + d.x + r.x;
  o.y = a.y + b.y + c.y + d.y + r.y;
  o.z = a.z + b.z + c.z + d.z + r.z;
  o.w = a.w + b.w + c.w + d.w + r.w;
  *(float4*)&out[i] = o;
}

// ---------------- RoPE (in-place, bf16), rotate_half, optional scale ----------------
__global__ __launch_bounds__(256) void rope_kernel(ushort* __restrict__ x,
                                                   const float* __restrict__ ct,
                                                   const float* __restrict__ st,
                                                   int nheads, float scale) {
  int idx = blockIdx.x * 256 + threadIdx.x;
  int d = idx & 63;
  int hh = (idx >> 6) % nheads;
  int s = idx / (64 * nheads);
  ushort* p = x + (size_t)s * (nheads * HD) + hh * HD + d;
  float x1 = bf2f(p[0]), x2 = bf2f(p[64]);
  float c = ct[s * HD + d], sn = st[s * HD + d];
  p[0] = f2bf((x1 * c - x2 * sn) * scale);
  p[64] = f2bf((x2 * c + x1 * sn) * scale);
}

// ---------------- Flash attention (causal, GQA 4:1) ----------------
__global__ __launch_bounds__(256) void attn_kernel(const ushort* __restrict__ q,
                                                   const ushort* __restrict__ k,
                                                   const ushort* __restrict__ vt,
                                                   ushort* __restrict__ o) {
  int qb = blockIdx.x, h = blockIdx.y, kvh = h >> 2;
  int tid = threadIdx.x, lane = tid & 63, wave = tid >> 6;
  __shared__ ushort Ks[64][136];
  __shared__ ushort Vs[128][72];
  __shared__ ushort Ps[4][16][72];

  bf16x8 qf[4];
  int qrow = qb * 64 + wave * 16 + (lane & 15);
#pragma unroll
  for (int kk = 0; kk < 4; kk++)
    qf[kk] = *(const bf16x8*)&q[(size_t)qrow * DIM + h * HD + kk * 32 + (lane >> 4) * 8];

  f32x4 oacc[8] = {};
  float mrow[4], lrow[4];
  int qr[4];
#pragma unroll
  for (int j = 0; j < 4; j++) {
    mrow[j] = -INFINITY; lrow[j] = 0.f;
    qr[j] = qb * 64 + wave * 16 + (lane >> 4) * 4 + j;
  }

  for (int kt = 0; kt <= qb; kt++) {
    int key0 = kt * 64;
#pragma unroll
    for (int c = 0; c < 4; c++) {
      int e = tid * 32 + c * 8;
      int r = e >> 7, cc = e & 127;
      *(bf16x8*)&Ks[r][cc] =
          *(const bf16x8*)&k[(size_t)(key0 + r) * (NKVH * HD) + kvh * HD + cc];
      int r2 = e >> 6, cc2 = e & 63;
      *(bf16x8*)&Vs[r2][cc2] =
          *(const bf16x8*)&vt[(size_t)(kvh * HD + r2) * SEQ + key0 + cc2];
    }
    __syncthreads();

    f32x4 sf[4] = {};
#pragma unroll
    for (int fn = 0; fn < 4; fn++)
#pragma unroll
      for (int kk = 0; kk < 4; kk++) {
        bf16x8 kf = *(const bf16x8*)&Ks[fn * 16 + (lane & 15)][kk * 32 + (lane >> 4) * 8];
        sf[fn] = __builtin_amdgcn_mfma_f32_16x16x32_bf16(qf[kk], kf, sf[fn], 0, 0, 0);
      }

#pragma unroll
    for (int fn = 0; fn < 4; fn++) {
      int key = key0 + fn * 16 + (lane & 15);
#pragma unroll
      for (int j = 0; j < 4; j++)
        if (key > qr[j]) sf[fn][j] = -INFINITY;
    }

#pragma unroll
    for (int j = 0; j < 4; j++) {
      float mx = fmaxf(fmaxf(sf[0][j], sf[1][j]), fmaxf(sf[2][j], sf[3][j]));
#pragma unroll
      for (int off = 1; off < 16; off <<= 1) mx = fmaxf(mx, __shfl_xor(mx, off));
      float mnew = fmaxf(mrow[j], mx);
      float sc = __expf(mrow[j] - mnew);
      mrow[j] = mnew;
      float rs = 0.f;
#pragma unroll
      for (int fn = 0; fn < 4; fn++) {
        float p = __expf(sf[fn][j] - mnew);
        sf[fn][j] = p;
        rs += p;
      }
#pragma unroll
      for (int off = 1; off < 16; off <<= 1) rs += __shfl_xor(rs, off);
      lrow[j] = lrow[j] * sc + rs;
#pragma unroll
      for (int f2 = 0; f2 < 8; f2++) oacc[f2][j] *= sc;
    }

#pragma unroll
    for (int fn = 0; fn < 4; fn++)
#pragma unroll
      for (int j = 0; j < 4; j++)
        Ps[wave][(lane >> 4) * 4 + j][fn * 16 + (lane & 15)] = f2bf(sf[fn][j]);

#pragma unroll
    for (int kk = 0; kk < 2; kk++) {
      bf16x8 pf = *(const bf16x8*)&Ps[wave][lane & 15][kk * 32 + (lane >> 4) * 8];
#pragma unroll
      for (int f2 = 0; f2 < 8; f2++) {
        bf16x8 vf = *(const bf16x8*)&Vs[f2 * 16 + (lane & 15)][kk * 32 + (lane >> 4) * 8];
        oacc[f2] = __builtin_amdgcn_mfma_f32_16x16x32_bf16(pf, vf, oacc[f2], 0, 0, 0);
      }
    }
    __syncthreads();
  }

#pragma unroll
  for (int j = 0; j < 4; j++) {
    float inv = 1.f / lrow[j];
#pragma unroll
    for (int f2 = 0; f2 < 8; f2++)
      o[(size_t)qr[j] * DIM + h * HD + f2 * 16 + (lane & 15)] = f2bf(oacc[f2][j] * inv);
  }
}

// ---------------- h = silu(gate) * up ----------------
__global__ __launch_bounds__(256) void silu_mul_kernel(const ushort* __restrict__ g,
                                                       const ushort* __restrict__ u,
                                                       ushort* __restrict__ h) {
  size_t idx = (size_t)(blockIdx.x * 256 + threadIdx.x) * 8;
  bf16x8 gv = *(const bf16x8*)&g[idx];
  bf16x8 uv = *(const bf16x8*)&u[idx];
  bf16x8 hv;
#pragma unroll
  for (int i = 0; i < 8; i++) {
    float gf = bf2f((ushort)gv[i]);
    float uf = bf2f((ushort)uv[i]);
    float sv = gf / (1.f + __expf(-gf));
    hv[i] = (short)f2bf(sv * uf);
  }
  *(bf16x8*)&h[idx] = hv;
}

extern "C" void kernel_launch(void* const* d_in, const int* in_sizes, int n_in,
                              void* d_out, int out_size, void* d_ws, size_t ws_size,
                              hipStream_t stream) {
  const float* x    = (const float*)d_in[0];
  const float* w1   = (const float*)d_in[1];
  const float* w2   = (const float*)d_in[2];
  const float* cosT = (const float*)d_in[3];
  const float* sinT = (const float*)d_in[4];
  const float* wq = (const float*)d_in[6];
  const float* la_q = (const float*)d_in[7];
  const float* lb_q = (const float*)d_in[8];
  const float* wk = (const float*)d_in[9];
  const float* la_k = (const float*)d_in[10];
  const float* lb_k = (const float*)d_in[11];
  const float* wv = (const float*)d_in[12];
  const float* la_v = (const float*)d_in[13];
  const float* lb_v = (const float*)d_in[14];
  const float* wo = (const float*)d_in[15];
  const float* la_o = (const float*)d_in[16];
  const float* lb_o = (const float*)d_in[17];
  const float* wg = (const float*)d_in[18];
  const float* la_g = (const float*)d_in[19];
  const float* lb_g = (const float*)d_in[20];
  const float* wu = (const float*)d_in[21];
  const float* la_u = (const float*)d_in[22];
  const float* lb_u = (const float*)d_in[23];
  const float* wd = (const float*)d_in[24];
  const float* la_d = (const float*)d_in[25];
  const float* lb_d = (const float*)d_in[26];
  float* out = (float*)d_out;

  char* ws = (char*)d_ws;
  ushort* xn1 = (ushort*)ws;  ws += (size_t)SEQ * DIM * 2;   // 8 MB
  ushort* qb  = (ushort*)ws;  ws += (size_t)SEQ * DIM * 2;   // 8 MB
  ushort* kb  = (ushort*)ws;  ws += (size_t)SEQ * NKVH * HD * 2;
  ushort* vtb = (ushort*)ws;  ws += (size_t)SEQ * NKVH * HD * 2;
  ushort* ob  = (ushort*)ws;  ws += (size_t)SEQ * DIM * 2;
  float*  xmed= (float*)ws;   ws += (size_t)SEQ * DIM * 4;   // 16 MB
  ushort* xn2 = (ushort*)ws;  ws += (size_t)SEQ * DIM * 2;   // 8 MB
  ushort* gate= (ushort*)ws;  ws += (size_t)SEQ * FF * 2;    // 28 MB
  ushort* up  = (ushort*)ws;  ws += (size_t)SEQ * FF * 2;    // 28 MB
  ushort* hb  = (ushort*)ws;  ws += (size_t)SEQ * FF * 2;    // 28 MB
  ushort* t_q = (ushort*)ws; ws += SEQ * LR * 2;
  ushort* t_k = (ushort*)ws; ws += SEQ * LR * 2;
  ushort* t_v = (ushort*)ws; ws += SEQ * LR * 2;
  ushort* t_o = (ushort*)ws; ws += SEQ * LR * 2;
  ushort* t_g = (ushort*)ws; ws += SEQ * LR * 2;
  ushort* t_u = (ushort*)ws; ws += SEQ * LR * 2;
  ushort* t_d = (ushort*)ws; ws += SEQ * LR * 2;
  ushort* wbf = (ushort*)ws; ws += (size_t)FF * DIM * 2;     // 112 MB rotating bf16 weights

  // split-K partial buffers aliased onto dead regions:
  float* pbuf1 = (float*)gate;  // QKV (50 MB) / wo (64 MB): gate..hb dead then
  float* pbuf2 = (float*)xn2;   // wd (64 MB): xn2+gate+up dead then, ends at hb

  size_t snd = (size_t)SEQ * DIM;

  auto cvt = [&](const float* w, ushort* dst, size_t n) {
    w_convert_kernel<<<2048, 256, 0, stream>>>(w, dst, n / 8);
  };

  // 1) norm + lora-A
  rmsnorm_kernel<<<SEQ, 256, 0, stream>>>(x, w1, xn1);
  lora_a_kernel<<<SEQ, 256, 0, stream>>>(xn1, la_q, t_q, DIM);
  lora_a_kernel<<<SEQ, 256, 0, stream>>>(xn1, la_k, t_k, DIM);
  lora_a_kernel<<<SEQ, 256, 0, stream>>>(xn1, la_v, t_v, DIM);

  // 2) fused QKV GEMM (N=6144, split-K2) -> partials -> routed reduce
  cvt(wq, wbf, (size_t)DIM * DIM);
  cvt(wk, wbf + (size_t)DIM * DIM, (size_t)1024 * DIM);
  cvt(wv, wbf + (size_t)(DIM + 1024) * DIM, (size_t)1024 * DIM);
  gemm256_kernel<3><<<dim3((DIM + 2048) / 256, SEQ / 256, 2), 512, 0, stream>>>(
      xn1, wbf, lb_q, lb_k, lb_v, t_q, t_k, t_v, DIM, DIM + 1024,
      pbuf1, SEQ, DIM + 2048, DIM, 32);
  reduce2_qkv_kernel<<<SEQ * (DIM + 2048) / 1024, 256, 0, stream>>>(pbuf1, qb, kb, vtb);

  // 3) RoPE (q pre-scaled by 1/sqrt(HD)) + attention
  rope_kernel<<<SEQ * NH * 64 / 256, 256, 0, stream>>>(qb, cosT, sinT, NH, 0.08838834764831845f);
  rope_kernel<<<SEQ * NKVH * 64 / 256, 256, 0, stream>>>(kb, cosT, sinT, NKVH, 1.0f);
  attn_kernel<<<dim3(SEQ / 64, NH), 256, 0, stream>>>(qb, kb, vtb, ob);

  // 4) WO (split-K4) + residual -> xmed
  lora_a_kernel<<<SEQ, 256, 0, stream>>>(ob, la_o, t_o, DIM);
  cvt(wo, wbf, (size_t)DIM * DIM);
  gemm256_kernel<3><<<dim3(DIM / 256, SEQ / 256, 4), 512, 0, stream>>>(
      ob, wbf, lb_o, lb_o, lb_o, t_o, t_o, t_o, DIM, DIM,
      pbuf1, SEQ, DIM, DIM, 16);
  reduce4_res_kernel<<<snd / 1024, 256, 0, stream>>>(pbuf1, x, xmed, snd);

  // 5) FFN
  rmsnorm_kernel<<<SEQ, 256, 0, stream>>>(xmed, w2, xn2);
  lora_a_kernel<<<SEQ, 256, 0, stream>>>(xn2, la_g, t_g, DIM);
  lora_a_kernel<<<SEQ, 256, 0, stream>>>(xn2, la_u, t_u, DIM);
  cvt(wg, wbf, (size_t)FF * DIM);
  gemm256_kernel<0><<<dim3(FF / 256, SEQ / 256, 1), 512, 0, stream>>>(
      xn2, wbf, lb_g, lb_g, lb_g, t_g, t_g, t_g, FF, FF,
      gate, SEQ, FF, DIM, DIM / 64);
  cvt(wu, wbf, (size_t)FF * DIM);
  gemm256_kernel<0><<<dim3(FF / 256, SEQ / 256, 1), 512, 0, stream>>>(
      xn2, wbf, lb_u, lb_u, lb_u, t_u, t_u, t_u, FF, FF,
      up, SEQ, FF, DIM, DIM / 64);
  silu_mul_kernel<<<SEQ * FF / 8 / 256, 256, 0, stream>>>(gate, up, hb);
  lora_a_kernel<<<SEQ, 256, 0, stream>>>(hb, la_d, t_d, FF);
  cvt(wd, wbf, (size_t)DIM * FF);
  gemm256_kernel<3><<<dim3(DIM / 256, SEQ / 256, 4), 512, 0, stream>>>(
      hb, wbf, lb_d, lb_d, lb_d, t_d, t_d, t_d, DIM, DIM,
      pbuf2, SEQ, DIM, FF, FF / 4 / 64);
  reduce4_res_kernel<<<snd / 1024, 256, 0, stream>>>(pbuf2, xmed, out, snd);
}

// Round 6
// 1331.549 us; speedup vs baseline: 2.3236x; 1.0457x over previous
//
#include <hip/hip_runtime.h>
#include <hip/hip_bf16.h>
#include <math.h>

#define SEQ 1024
#define DIM 4096
#define NH 32
#define HD 128
#define NKVH 8
#define FF 14336
#define LR 16

typedef __attribute__((ext_vector_type(8))) short bf16x8;
typedef __attribute__((ext_vector_type(4))) float f32x4;
typedef __attribute__((ext_vector_type(4))) ushort ushort4v;

__device__ __forceinline__ ushort f2bf(float f) {
  union { float f; unsigned u; } v; v.f = f;
  unsigned r = (v.u + 0x7FFFu + ((v.u >> 16) & 1u)) >> 16;
  return (ushort)r;
}
__device__ __forceinline__ float bf2f(ushort h) {
  union { unsigned u; float f; } v; v.u = ((unsigned)h) << 16;
  return v.f;
}

__device__ __forceinline__ void gload_lds16(const void* g, void* l) {
  __builtin_amdgcn_global_load_lds(
      (const __attribute__((address_space(1))) void*)g,
      (__attribute__((address_space(3))) void*)l, 16, 0, 0);
}

// ---------------- RMSNorm: f32 in -> bf16 out ----------------
__global__ __launch_bounds__(256) void rmsnorm_kernel(const float* __restrict__ x,
                                                      const float* __restrict__ w,
                                                      ushort* __restrict__ out) {
  int row = blockIdx.x;
  int tid = threadIdx.x;
  const float* xr = x + (size_t)row * DIM;
  float vals[16];
  float s = 0.f;
#pragma unroll
  for (int c = 0; c < 4; c++) {
    float4 v = *(const float4*)&xr[(tid + c * 256) * 4];
    vals[c * 4 + 0] = v.x; vals[c * 4 + 1] = v.y;
    vals[c * 4 + 2] = v.z; vals[c * 4 + 3] = v.w;
    s += v.x * v.x + v.y * v.y + v.z * v.z + v.w * v.w;
  }
#pragma unroll
  for (int off = 32; off >= 1; off >>= 1) s += __shfl_down(s, off);
  __shared__ float wsum[4];
  __shared__ float scale_s;
  int lane = tid & 63, wv = tid >> 6;
  if (lane == 0) wsum[wv] = s;
  __syncthreads();
  if (tid == 0) {
    float t = wsum[0] + wsum[1] + wsum[2] + wsum[3];
    scale_s = rsqrtf(t / (float)DIM + 1e-5f);
  }
  __syncthreads();
  float scale = scale_s;
  ushort* orow = out + (size_t)row * DIM;
#pragma unroll
  for (int c = 0; c < 4; c++) {
    int base = (tid + c * 256) * 4;
    float4 wv4 = *(const float4*)&w[base];
    ushort4v ov;
    ov.x = f2bf(vals[c * 4 + 0] * scale * wv4.x);
    ov.y = f2bf(vals[c * 4 + 1] * scale * wv4.y);
    ov.z = f2bf(vals[c * 4 + 2] * scale * wv4.z);
    ov.w = f2bf(vals[c * 4 + 3] * scale * wv4.w);
    *(ushort4v*)&orow[base] = ov;
  }
}

// ---------------- LoRA A: tbf[M][16] = A(bf16 M x K) @ la(K x 16), bf16 out ----------------
__global__ __launch_bounds__(256) void lora_a_kernel(const ushort* __restrict__ A,
                                                     const float* __restrict__ la,
                                                     ushort* __restrict__ tbf, int K) {
  int m = blockIdx.x, i = threadIdx.x;
  float acc[16];
#pragma unroll
  for (int n = 0; n < 16; n++) acc[n] = 0.f;
  for (int base = i * 16; base < K; base += 256 * 16) {
    bf16x8 a0 = *(const bf16x8*)&A[(size_t)m * K + base];
    bf16x8 a1 = *(const bf16x8*)&A[(size_t)m * K + base + 8];
    const float* lp = la + (size_t)base * LR;
#pragma unroll
    for (int kk = 0; kk < 16; kk++) {
      float av = bf2f((ushort)(kk < 8 ? a0[kk] : a1[kk - 8]));
#pragma unroll
      for (int n = 0; n < 16; n += 4) {
        float4 l = *(const float4*)&lp[kk * LR + n];
        acc[n] += av * l.x; acc[n + 1] += av * l.y;
        acc[n + 2] += av * l.z; acc[n + 3] += av * l.w;
      }
    }
  }
  __shared__ float red[256][16];
  __shared__ float red2[16][16];
#pragma unroll
  for (int n = 0; n < 16; n++) red[i][n] = acc[n];
  __syncthreads();
  {
    int g = i >> 4, n = i & 15;
    float s = 0.f;
#pragma unroll
    for (int j = 0; j < 16; j++) s += red[g * 16 + j][n];
    red2[g][n] = s;
  }
  __syncthreads();
  if (i < 16) {
    float s = 0.f;
#pragma unroll
    for (int g = 0; g < 16; g++) s += red2[g][i];
    tbf[(size_t)m * LR + i] = f2bf(s);
  }
}

// ================= 256x256 GEMM, 8 waves, 2-phase dbuf, fused f32->bf16 dequant =================
// out = A(M x K, bf16) @ W(N x K, f32)^T  [+ lora K-ext when z==0]
// A staged via global_load_lds (source pre-swizzle); W reg-staged (load f32 early,
// cvt+swizzled ds_write after MFMA = T14 async split). Counted vmcnt: 12 / 4.
// Weight/lb/t segments by col: [0,c1)->(W0,lb0,t0); [c1,c2)->(W1,lb1,t1); [c2,N)->(W2,lb2,t2)
// WM 0: bf16 direct [M][N];  WM 3: f32 partial slice [z][M][N]
template <int WM>
__global__ __launch_bounds__(512) void gemm256_kernel(
    const ushort* __restrict__ A,
    const float* __restrict__ W0, const float* __restrict__ W1, const float* __restrict__ W2,
    const float* __restrict__ lb0, const float* __restrict__ lb1, const float* __restrict__ lb2,
    const ushort* __restrict__ t0, const ushort* __restrict__ t1, const ushort* __restrict__ t2,
    int c1, int c2, void* __restrict__ outp, int M, int N, int K, int nkp) {
  __shared__ __align__(16) ushort As[2][256 * 64];
  __shared__ __align__(16) ushort Bs[2][256 * 64];
  int tid = threadIdx.x;
  int lane = tid & 63, wave = tid >> 6;
  int wm = wave >> 2, wn = wave & 3;

  // ---- T1: bijective XCD swizzle of flattened block index ----
  int gx = gridDim.x, gy = gridDim.y;
  int flat = blockIdx.x + gx * (blockIdx.y + gy * blockIdx.z);
  int nwg = gx * gy * gridDim.z;
  int q = nwg >> 3, r = nwg & 7;
  int xcd = flat & 7;
  int wgid = (xcd < r ? xcd * (q + 1) : r * (q + 1) + (xcd - r) * q) + (flat >> 3);
  int bx = wgid % gx;
  int tmp = wgid / gx;
  int by = tmp % gy;
  int z = tmp / gy;

  int n0 = bx * 256, m0 = by * 256;
  int k0 = z * nkp;

  // segment select for weight / lora
  const float* Wp; const float* lbp; const ushort* tp; int nseg, wseg;
  if (n0 < c1)      { Wp = W0; lbp = lb0; tp = t0; nseg = n0;      wseg = c1; }
  else if (n0 < c2) { Wp = W1; lbp = lb1; tp = t1; nseg = n0 - c1; wseg = c2 - c1; }
  else              { Wp = W2; lbp = lb2; tp = t2; nseg = n0 - c2; wseg = N - c2; }

  // A staging (global_load_lds, linear dest, source pre-swizzled)
  int srow = tid >> 3;                     // 0..63
  int sswz = ((tid & 7) ^ (srow & 7)) * 8; // inverse-swizzled source col
  const ushort* Ab = A + (size_t)(m0 + srow) * K + sswz;
  // B reg-staging source (no pre-swizzle; swizzle applied at ds_write)
  int cg = tid & 7;                        // 8-f32 col group
  const float* Wb = Wp + (size_t)(nseg + srow) * K + cg * 8;
  int phys = (tid & 7) ^ (srow & 7);       // swizzled write slot (same for all i)

  f32x4 acc[8][4] = {};
  float4 breg[4][2];

#define ISSUE_B(kt)                                                           \
  _Pragma("unroll") for (int i = 0; i < 4; i++) {                             \
    const float* gp = Wb + (size_t)(i * 64) * K + (size_t)(kt) * 64;          \
    breg[i][0] = *(const float4*)gp;                                          \
    breg[i][1] = *(const float4*)(gp + 4);                                    \
  }
#define ISSUE_A(kt, b)                                                        \
  _Pragma("unroll") for (int i = 0; i < 4; i++) {                             \
    gload_lds16(Ab + (size_t)(i * 64) * K + (size_t)(kt) * 64,                \
                &As[b][wave * 512 + i * 4096]);                               \
  }
#define WRITE_B(b)                                                            \
  _Pragma("unroll") for (int i = 0; i < 4; i++) {                             \
    bf16x8 v;                                                                 \
    v[0] = (short)f2bf(breg[i][0].x); v[1] = (short)f2bf(breg[i][0].y);       \
    v[2] = (short)f2bf(breg[i][0].z); v[3] = (short)f2bf(breg[i][0].w);       \
    v[4] = (short)f2bf(breg[i][1].x); v[5] = (short)f2bf(breg[i][1].y);       \
    v[6] = (short)f2bf(breg[i][1].z); v[7] = (short)f2bf(breg[i][1].w);       \
    *(bf16x8*)&Bs[b][(i * 64 + srow) * 64 + phys * 8] = v;                    \
  }
#define LDFRAG(buf, rr, ks) \
  (*(const bf16x8*)&(buf)[(rr) * 64 + (((ks) * 4 + (lane >> 4)) ^ ((rr) & 7)) * 8])

  // ---- prologue: tile k0 into buf 0 ----
  ISSUE_B(k0);
  asm volatile("" ::: "memory");  // pin order: B loads before A gloads
  ISSUE_A(k0, 0);
  asm volatile("s_waitcnt vmcnt(4)" ::: "memory");  // B(k0) regs ready, A(k0) in flight
  WRITE_B(0);
  asm volatile("s_waitcnt lgkmcnt(0)" ::: "memory");

  for (int t = 0; t < nkp; t++) {
    int cur = t & 1;
    if (t + 1 < nkp) {
      ISSUE_B(k0 + t + 1);
      asm volatile("" ::: "memory");
      ISSUE_A(k0 + t + 1, cur ^ 1);
      asm volatile("s_waitcnt vmcnt(12)" ::: "memory");  // drain A(t); keep B/A(t+1)
    } else {
      asm volatile("s_waitcnt vmcnt(0)" ::: "memory");
    }
    __builtin_amdgcn_s_barrier();
    __builtin_amdgcn_sched_barrier(0);
    const ushort* as = As[cur];
    const ushort* bs = Bs[cur];
#pragma unroll
    for (int ks = 0; ks < 2; ks++) {
      bf16x8 af[8], bfr[4];
#pragma unroll
      for (int f = 0; f < 8; f++) {
        int ra = wm * 128 + f * 16 + (lane & 15);
        af[f] = LDFRAG(as, ra, ks);
      }
#pragma unroll
      for (int f = 0; f < 4; f++) {
        int rb = wn * 64 + f * 16 + (lane & 15);
        bfr[f] = LDFRAG(bs, rb, ks);
      }
      __builtin_amdgcn_s_setprio(1);
#pragma unroll
      for (int fm = 0; fm < 8; fm++)
#pragma unroll
        for (int fn = 0; fn < 4; fn++)
          acc[fm][fn] = __builtin_amdgcn_mfma_f32_16x16x32_bf16(af[fm], bfr[fn], acc[fm][fn], 0, 0, 0);
      __builtin_amdgcn_s_setprio(0);
    }
    if (t + 1 < nkp) {
      asm volatile("s_waitcnt vmcnt(4)" ::: "memory");  // B(t+1) regs ready; A(t+1) in flight
      WRITE_B(cur ^ 1);
      asm volatile("s_waitcnt lgkmcnt(0)" ::: "memory");
    }
    __builtin_amdgcn_sched_barrier(0);
    __builtin_amdgcn_s_barrier();
  }
#undef ISSUE_B
#undef ISSUE_A
#undef WRITE_B

  // ---- LoRA K-extension (split 0 only): K=32 slice, A=[t|0], B=[lb^T|0] ----
  if (z == 0) {
#pragma unroll
    for (int it = 0; it < 2; it++) {
      int task = tid + it * 512;  // 256 rows x 4 slots
      int rr = task >> 2, ls = task & 3;
      int ph = ls ^ (rr & 7);
      bf16x8 avv = {};
      bf16x8 bvv = {};
      if (ls < 2) {
        avv = *(const bf16x8*)&tp[(size_t)(m0 + rr) * LR + ls * 8];
#pragma unroll
        for (int j = 0; j < 8; j++)
          bvv[j] = (short)f2bf(lbp[(size_t)(ls * 8 + j) * wseg + nseg + rr]);
      }
      *(bf16x8*)&As[0][rr * 64 + ph * 8] = avv;
      *(bf16x8*)&Bs[0][rr * 64 + ph * 8] = bvv;
    }
    __syncthreads();
    bf16x8 af[8], bfr[4];
#pragma unroll
    for (int f = 0; f < 8; f++) {
      int ra = wm * 128 + f * 16 + (lane & 15);
      af[f] = LDFRAG(As[0], ra, 0);
    }
#pragma unroll
    for (int f = 0; f < 4; f++) {
      int rb = wn * 64 + f * 16 + (lane & 15);
      bfr[f] = LDFRAG(Bs[0], rb, 0);
    }
#pragma unroll
    for (int fm = 0; fm < 8; fm++)
#pragma unroll
      for (int fn = 0; fn < 4; fn++)
        acc[fm][fn] = __builtin_amdgcn_mfma_f32_16x16x32_bf16(af[fm], bfr[fn], acc[fm][fn], 0, 0, 0);
  }
#undef LDFRAG

  // ---- write ----
#pragma unroll
  for (int fm = 0; fm < 8; fm++) {
#pragma unroll
    for (int j = 0; j < 4; j++) {
      int mg = m0 + wm * 128 + fm * 16 + (lane >> 4) * 4 + j;
#pragma unroll
      for (int fn = 0; fn < 4; fn++) {
        int ng = n0 + wn * 64 + fn * 16 + (lane & 15);
        float v = acc[fm][fn][j];
        if (WM == 0) {
          ((ushort*)outp)[(size_t)mg * N + ng] = f2bf(v);
        } else {
          ((float*)outp)[((size_t)z * M + mg) * (size_t)N + ng] = v;
        }
      }
    }
  }
}

// ---------------- split-K reduces ----------------
// QKV fused: p has 2 slices of [M][6144]; route cols to qb / kb / vt(transposed)
__global__ __launch_bounds__(256) void reduce2_qkv_kernel(const float* __restrict__ p,
                                                          ushort* __restrict__ qb,
                                                          ushort* __restrict__ kb,
                                                          ushort* __restrict__ vtb) {
  size_t i4 = ((size_t)blockIdx.x * 256 + threadIdx.x) * 4;
  size_t sstride = (size_t)SEQ * 6144;
  int m = (int)(i4 / 6144);
  int c = (int)(i4 % 6144);
  float4 a = *(const float4*)&p[i4];
  float4 b = *(const float4*)&p[i4 + sstride];
  float4 s;
  s.x = a.x + b.x; s.y = a.y + b.y; s.z = a.z + b.z; s.w = a.w + b.w;
  if (c < DIM) {
    ushort4v o;
    o.x = f2bf(s.x); o.y = f2bf(s.y); o.z = f2bf(s.z); o.w = f2bf(s.w);
    *(ushort4v*)&qb[(size_t)m * DIM + c] = o;
  } else if (c < DIM + 1024) {
    ushort4v o;
    o.x = f2bf(s.x); o.y = f2bf(s.y); o.z = f2bf(s.z); o.w = f2bf(s.w);
    *(ushort4v*)&kb[(size_t)m * 1024 + (c - DIM)] = o;
  } else {
    int n = c - DIM - 1024;
    vtb[(size_t)(n + 0) * SEQ + m] = f2bf(s.x);
    vtb[(size_t)(n + 1) * SEQ + m] = f2bf(s.y);
    vtb[(size_t)(n + 2) * SEQ + m] = f2bf(s.z);
    vtb[(size_t)(n + 3) * SEQ + m] = f2bf(s.w);
  }
}

__global__ __launch_bounds__(256) void reduce4_res_kernel(const float* __restrict__ p,
                                                          const float* __restrict__ res,
                                                          float* __restrict__ out,
                                                          size_t sstride) {
  size_t i = ((size_t)blockIdx.x * 256 + threadIdx.x) * 4;
  float4 a = *(const float4*)&p[i];
  float4 b = *(const float4*)&p[i + sstride];
  float4 c = *(const float4*)&p[i + 2 * sstride];
  float4 d = *(const float4*)&p[i + 3 * sstride];
  float4 r = *(const float4*)&res[i];
  float4 o;
  o.x = a.x + b.x + c.x + d.x + r.x;
  o.y = a.y + b.y + c.y + d.y + r.y;
  o.z = a.z + b.z + c.z + d.z + r.z;
  o.w = a.w + b.w + c.w + d.w + r.w;
  *(float4*)&out[i] = o;
}

// ---------------- RoPE (in-place, bf16), rotate_half, optional scale ----------------
__global__ __launch_bounds__(256) void rope_kernel(ushort* __restrict__ x,
                                                   const float* __restrict__ ct,
                                                   const float* __restrict__ st,
                                                   int nheads, float scale) {
  int idx = blockIdx.x * 256 + threadIdx.x;
  int d = idx & 63;
  int hh = (idx >> 6) % nheads;
  int s = idx / (64 * nheads);
  ushort* p = x + (size_t)s * (nheads * HD) + hh * HD + d;
  float x1 = bf2f(p[0]), x2 = bf2f(p[64]);
  float c = ct[s * HD + d], sn = st[s * HD + d];
  p[0] = f2bf((x1 * c - x2 * sn) * scale);
  p[64] = f2bf((x2 * c + x1 * sn) * scale);
}

// ---------------- Flash attention (causal, GQA 4:1) ----------------
__global__ __launch_bounds__(256) void attn_kernel(const ushort* __restrict__ q,
                                                   const ushort* __restrict__ k,
                                                   const ushort* __restrict__ vt,
                                                   ushort* __restrict__ o) {
  int qb = blockIdx.x, h = blockIdx.y, kvh = h >> 2;
  int tid = threadIdx.x, lane = tid & 63, wave = tid >> 6;
  __shared__ ushort Ks[64][136];
  __shared__ ushort Vs[128][72];
  __shared__ ushort Ps[4][16][72];

  bf16x8 qf[4];
  int qrow = qb * 64 + wave * 16 + (lane & 15);
#pragma unroll
  for (int kk = 0; kk < 4; kk++)
    qf[kk] = *(const bf16x8*)&q[(size_t)qrow * DIM + h * HD + kk * 32 + (lane >> 4) * 8];

  f32x4 oacc[8] = {};
  float mrow[4], lrow[4];
  int qr[4];
#pragma unroll
  for (int j = 0; j < 4; j++) {
    mrow[j] = -INFINITY; lrow[j] = 0.f;
    qr[j] = qb * 64 + wave * 16 + (lane >> 4) * 4 + j;
  }

  for (int kt = 0; kt <= qb; kt++) {
    int key0 = kt * 64;
#pragma unroll
    for (int c = 0; c < 4; c++) {
      int e = tid * 32 + c * 8;
      int r = e >> 7, cc = e & 127;
      *(bf16x8*)&Ks[r][cc] =
          *(const bf16x8*)&k[(size_t)(key0 + r) * (NKVH * HD) + kvh * HD + cc];
      int r2 = e >> 6, cc2 = e & 63;
      *(bf16x8*)&Vs[r2][cc2] =
          *(const bf16x8*)&vt[(size_t)(kvh * HD + r2) * SEQ + key0 + cc2];
    }
    __syncthreads();

    f32x4 sf[4] = {};
#pragma unroll
    for (int fn = 0; fn < 4; fn++)
#pragma unroll
      for (int kk = 0; kk < 4; kk++) {
        bf16x8 kf = *(const bf16x8*)&Ks[fn * 16 + (lane & 15)][kk * 32 + (lane >> 4) * 8];
        sf[fn] = __builtin_amdgcn_mfma_f32_16x16x32_bf16(qf[kk], kf, sf[fn], 0, 0, 0);
      }

#pragma unroll
    for (int fn = 0; fn < 4; fn++) {
      int key = key0 + fn * 16 + (lane & 15);
#pragma unroll
      for (int j = 0; j < 4; j++)
        if (key > qr[j]) sf[fn][j] = -INFINITY;
    }

#pragma unroll
    for (int j = 0; j < 4; j++) {
      float mx = fmaxf(fmaxf(sf[0][j], sf[1][j]), fmaxf(sf[2][j], sf[3][j]));
#pragma unroll
      for (int off = 1; off < 16; off <<= 1) mx = fmaxf(mx, __shfl_xor(mx, off));
      float mnew = fmaxf(mrow[j], mx);
      float sc = __expf(mrow[j] - mnew);
      mrow[j] = mnew;
      float rs = 0.f;
#pragma unroll
      for (int fn = 0; fn < 4; fn++) {
        float p = __expf(sf[fn][j] - mnew);
        sf[fn][j] = p;
        rs += p;
      }
#pragma unroll
      for (int off = 1; off < 16; off <<= 1) rs += __shfl_xor(rs, off);
      lrow[j] = lrow[j] * sc + rs;
#pragma unroll
      for (int f2 = 0; f2 < 8; f2++) oacc[f2][j] *= sc;
    }

#pragma unroll
    for (int fn = 0; fn < 4; fn++)
#pragma unroll
      for (int j = 0; j < 4; j++)
        Ps[wave][(lane >> 4) * 4 + j][fn * 16 + (lane & 15)] = f2bf(sf[fn][j]);

#pragma unroll
    for (int kk = 0; kk < 2; kk++) {
      bf16x8 pf = *(const bf16x8*)&Ps[wave][lane & 15][kk * 32 + (lane >> 4) * 8];
#pragma unroll
      for (int f2 = 0; f2 < 8; f2++) {
        bf16x8 vf = *(const bf16x8*)&Vs[f2 * 16 + (lane & 15)][kk * 32 + (lane >> 4) * 8];
        oacc[f2] = __builtin_amdgcn_mfma_f32_16x16x32_bf16(pf, vf, oacc[f2], 0, 0, 0);
      }
    }
    __syncthreads();
  }

#pragma unroll
  for (int j = 0; j < 4; j++) {
    float inv = 1.f / lrow[j];
#pragma unroll
    for (int f2 = 0; f2 < 8; f2++)
      o[(size_t)qr[j] * DIM + h * HD + f2 * 16 + (lane & 15)] = f2bf(oacc[f2][j] * inv);
  }
}

// ---------------- h = silu(gate) * up ----------------
__global__ __launch_bounds__(256) void silu_mul_kernel(const ushort* __restrict__ g,
                                                       const ushort* __restrict__ u,
                                                       ushort* __restrict__ h) {
  size_t idx = (size_t)(blockIdx.x * 256 + threadIdx.x) * 8;
  bf16x8 gv = *(const bf16x8*)&g[idx];
  bf16x8 uv = *(const bf16x8*)&u[idx];
  bf16x8 hv;
#pragma unroll
  for (int i = 0; i < 8; i++) {
    float gf = bf2f((ushort)gv[i]);
    float uf = bf2f((ushort)uv[i]);
    float sv = gf / (1.f + __expf(-gf));
    hv[i] = (short)f2bf(sv * uf);
  }
  *(bf16x8*)&h[idx] = hv;
}

extern "C" void kernel_launch(void* const* d_in, const int* in_sizes, int n_in,
                              void* d_out, int out_size, void* d_ws, size_t ws_size,
                              hipStream_t stream) {
  const float* x    = (const float*)d_in[0];
  const float* w1   = (const float*)d_in[1];
  const float* w2   = (const float*)d_in[2];
  const float* cosT = (const float*)d_in[3];
  const float* sinT = (const float*)d_in[4];
  const float* wq = (const float*)d_in[6];
  const float* la_q = (const float*)d_in[7];
  const float* lb_q = (const float*)d_in[8];
  const float* wk = (const float*)d_in[9];
  const float* la_k = (const float*)d_in[10];
  const float* lb_k = (const float*)d_in[11];
  const float* wv = (const float*)d_in[12];
  const float* la_v = (const float*)d_in[13];
  const float* lb_v = (const float*)d_in[14];
  const float* wo = (const float*)d_in[15];
  const float* la_o = (const float*)d_in[16];
  const float* lb_o = (const float*)d_in[17];
  const float* wg = (const float*)d_in[18];
  const float* la_g = (const float*)d_in[19];
  const float* lb_g = (const float*)d_in[20];
  const float* wu = (const float*)d_in[21];
  const float* la_u = (const float*)d_in[22];
  const float* lb_u = (const float*)d_in[23];
  const float* wd = (const float*)d_in[24];
  const float* la_d = (const float*)d_in[25];
  const float* lb_d = (const float*)d_in[26];
  float* out = (float*)d_out;

  char* ws = (char*)d_ws;
  ushort* xn1 = (ushort*)ws;  ws += (size_t)SEQ * DIM * 2;   // 8 MB
  ushort* qb  = (ushort*)ws;  ws += (size_t)SEQ * DIM * 2;   // 8 MB
  ushort* kb  = (ushort*)ws;  ws += (size_t)SEQ * NKVH * HD * 2;
  ushort* vtb = (ushort*)ws;  ws += (size_t)SEQ * NKVH * HD * 2;
  ushort* ob  = (ushort*)ws;  ws += (size_t)SEQ * DIM * 2;
  float*  xmed= (float*)ws;   ws += (size_t)SEQ * DIM * 4;   // 16 MB
  ushort* xn2 = (ushort*)ws;  ws += (size_t)SEQ * DIM * 2;   // 8 MB
  ushort* gate= (ushort*)ws;  ws += (size_t)SEQ * FF * 2;    // 28 MB
  ushort* up  = (ushort*)ws;  ws += (size_t)SEQ * FF * 2;    // 28 MB
  ushort* hb  = (ushort*)ws;  ws += (size_t)SEQ * FF * 2;    // 28 MB
  ushort* t_q = (ushort*)ws; ws += SEQ * LR * 2;
  ushort* t_k = (ushort*)ws; ws += SEQ * LR * 2;
  ushort* t_v = (ushort*)ws; ws += SEQ * LR * 2;
  ushort* t_o = (ushort*)ws; ws += SEQ * LR * 2;
  ushort* t_g = (ushort*)ws; ws += SEQ * LR * 2;
  ushort* t_u = (ushort*)ws; ws += SEQ * LR * 2;
  ushort* t_d = (ushort*)ws; ws += SEQ * LR * 2;

  // split-K partial buffers aliased onto dead regions:
  float* pbuf1 = (float*)gate;  // QKV (50 MB) / wo (64 MB): gate..hb dead then
  float* pbuf2 = (float*)xn2;   // wd (64 MB): xn2+gate+up dead then, ends at hb

  size_t snd = (size_t)SEQ * DIM;

  // 1) norm + lora-A
  rmsnorm_kernel<<<SEQ, 256, 0, stream>>>(x, w1, xn1);
  lora_a_kernel<<<SEQ, 256, 0, stream>>>(xn1, la_q, t_q, DIM);
  lora_a_kernel<<<SEQ, 256, 0, stream>>>(xn1, la_k, t_k, DIM);
  lora_a_kernel<<<SEQ, 256, 0, stream>>>(xn1, la_v, t_v, DIM);

  // 2) fused QKV GEMM (N=6144, split-K2, fused dequant) -> routed reduce
  gemm256_kernel<3><<<dim3((DIM + 2048) / 256, SEQ / 256, 2), 512, 0, stream>>>(
      xn1, wq, wk, wv, lb_q, lb_k, lb_v, t_q, t_k, t_v, DIM, DIM + 1024,
      pbuf1, SEQ, DIM + 2048, DIM, 32);
  reduce2_qkv_kernel<<<SEQ * (DIM + 2048) / 1024, 256, 0, stream>>>(pbuf1, qb, kb, vtb);

  // 3) RoPE (q pre-scaled by 1/sqrt(HD)) + attention
  rope_kernel<<<SEQ * NH * 64 / 256, 256, 0, stream>>>(qb, cosT, sinT, NH, 0.08838834764831845f);
  rope_kernel<<<SEQ * NKVH * 64 / 256, 256, 0, stream>>>(kb, cosT, sinT, NKVH, 1.0f);
  attn_kernel<<<dim3(SEQ / 64, NH), 256, 0, stream>>>(qb, kb, vtb, ob);

  // 4) WO (split-K4) + residual -> xmed
  lora_a_kernel<<<SEQ, 256, 0, stream>>>(ob, la_o, t_o, DIM);
  gemm256_kernel<3><<<dim3(DIM / 256, SEQ / 256, 4), 512, 0, stream>>>(
      ob, wo, wo, wo, lb_o, lb_o, lb_o, t_o, t_o, t_o, DIM, DIM,
      pbuf1, SEQ, DIM, DIM, 16);
  reduce4_res_kernel<<<snd / 1024, 256, 0, stream>>>(pbuf1, x, xmed, snd);

  // 5) FFN
  rmsnorm_kernel<<<SEQ, 256, 0, stream>>>(xmed, w2, xn2);
  lora_a_kernel<<<SEQ, 256, 0, stream>>>(xn2, la_g, t_g, DIM);
  lora_a_kernel<<<SEQ, 256, 0, stream>>>(xn2, la_u, t_u, DIM);
  gemm256_kernel<0><<<dim3(FF / 256, SEQ / 256, 1), 512, 0, stream>>>(
      xn2, wg, wg, wg, lb_g, lb_g, lb_g, t_g, t_g, t_g, FF, FF,
      gate, SEQ, FF, DIM, DIM / 64);
  gemm256_kernel<0><<<dim3(FF / 256, SEQ / 256, 1), 512, 0, stream>>>(
      xn2, wu, wu, wu, lb_u, lb_u, lb_u, t_u, t_u, t_u, FF, FF,
      up, SEQ, FF, DIM, DIM / 64);
  silu_mul_kernel<<<SEQ * FF / 8 / 256, 256, 0, stream>>>(gate, up, hb);
  lora_a_kernel<<<SEQ, 256, 0, stream>>>(hb, la_d, t_d, FF);
  gemm256_kernel<3><<<dim3(DIM / 256, SEQ / 256, 4), 512, 0, stream>>>(
      hb, wd, wd, wd, lb_d, lb_d, lb_d, t_d, t_d, t_d, DIM, DIM,
      pbuf2, SEQ, DIM, FF, FF / 4 / 64);
  reduce4_res_kernel<<<snd / 1024, 256, 0, stream>>>(pbuf2, xmed, out, snd);
}